// Round 4
// baseline (438.546 us; speedup 1.0000x reference)
//
#include <hip/hip_runtime.h>
#include <hip/hip_bf16.h>

typedef __hip_bfloat16 bf16;
typedef short bf16x8 __attribute__((ext_vector_type(8)));
typedef float f32x4 __attribute__((ext_vector_type(4)));

#define BBATCH 8
#define HHH 56
#define WWW 56
#define CCH 96          // C
#define DIN 192         // D
#define NST 16          // N
#define KDIR 4          // K
#define RDT 6           // R
#define LLEN 3136       // H*W
#define BLTOT 25088     // B*L
#define SSEG 64         // segments
#define SEGL 49         // L / SSEG
#define PJC 38          // R + 2N
#define PJW 152         // K * PJC
#define PJS 40          // padded LDS row stride (16B aligned)
#define PJS1 24         // pass-1 padded row stride (r+B only)
#define MLPH 384

// native exp2/log2 (v_exp_f32 / v_log_f32) with safe fallbacks
#if defined(__has_builtin)
#if __has_builtin(__builtin_amdgcn_exp2f)
#define EXP2F(x) __builtin_amdgcn_exp2f(x)
#endif
#if __has_builtin(__builtin_amdgcn_logf)
#define LOG2F_(x) __builtin_amdgcn_logf(x)
#endif
#endif
#ifndef EXP2F
#define EXP2F(x) __expf((x) * 0.69314718056f)
#endif
#ifndef LOG2F_
#define LOG2F_(x) (__logf(x) * 1.44269504f)
#endif
#define LOG2E 1.44269504f

__device__ __forceinline__ float b2f(bf16 v) { return __bfloat162float(v); }
__device__ __forceinline__ bf16  f2b(float v) { return __float2bfloat16(v); }
__device__ __forceinline__ unsigned short f2bu(float f) {
    union { bf16 h; unsigned short u; } c; c.h = __float2bfloat16(f); return c.u;
}
__device__ __forceinline__ float sigm(float x) { return 1.f / (1.f + __expf(-x)); }
__device__ __forceinline__ float softplusf(float x) {
    float t = EXP2F(-fabsf(x) * LOG2E);
    return fmaxf(x, 0.f) + 0.69314718f * LOG2F_(1.f + t);
}
__device__ __forceinline__ float geluf(float v) {
    float u = 0.7978845608028654f * (v + 0.044715f * v * v * v);
    float ey = __expf(2.f * u);
    float th = 1.f - 2.f / (ey + 1.f);
    return 0.5f * v * (1.f + th);
}

// scan-step l -> spatial position (row-major h*56+w) for direction k
__device__ __forceinline__ int pos_map(int k, int l) {
    if (k & 2) l = LLEN - 1 - l;
    if (k & 1) { int q = l / WWW; int r = l - q * WWW; return r * WWW + q; }
    return l;
}

// ---- LN: one wave per row of 96, emit bf16 ---------------------------------
__global__ __launch_bounds__(256) void ln_rows(
    const float* __restrict__ xin, const float* __restrict__ w,
    const float* __restrict__ b, unsigned short* __restrict__ xn) {
    int row = blockIdx.x * 4 + (threadIdx.x >> 6);
    int lane = threadIdx.x & 63;
    const float* xr = xin + (size_t)row * 96;
    float2 v = make_float2(0.f, 0.f);
    if (lane < 48) v = *(const float2*)&xr[lane * 2];
    float s = v.x + v.y, s2 = v.x * v.x + v.y * v.y;
    for (int o = 32; o; o >>= 1) {
        s += __shfl_down(s, o);
        s2 += __shfl_down(s2, o);
    }
    s = __shfl(s, 0); s2 = __shfl(s2, 0);
    float m = s * (1.f / 96.f);
    float var = s2 * (1.f / 96.f) - m * m;
    float rs = rsqrtf(var + 1e-5f);
    if (lane < 48) {
        float o0 = (v.x - m) * rs * w[lane * 2] + b[lane * 2];
        float o1 = (v.y - m) * rs * w[lane * 2 + 1] + b[lane * 2 + 1];
        ushort2 u; u.x = f2bu(o0); u.y = f2bu(o1);
        *(ushort2*)&xn[(size_t)row * 96 + lane * 2] = u;
    }
}

// ---- Unified MFMA GEMM: C[M=25088][N] = X[M][K](bf16) . W[N][K]^T(f32) -----
// block: 4 waves, each wave one 64-row M-strip, 4x4 frags -> 256M x 64N tile.
// EPI: 0=split xc/z  1=proj f32  2=+res f32  3=gelu(+bias) bf16  4=+bias+res f32
template<int N, int K, int EPI>
__global__ __launch_bounds__(256) void gemm_mfma(
    const unsigned short* __restrict__ X, const float* __restrict__ W,
    const float* __restrict__ bias, const float* __restrict__ res,
    void* __restrict__ out0v, void* __restrict__ out1v) {
    __shared__ unsigned short a_sh[256 * 40];
    __shared__ unsigned short b_sh[64 * 40];
    const int t = threadIdx.x;
    const int P0 = blockIdx.x * 256;
    const int N0 = blockIdx.y * 64;
    const int w = t >> 6, lane = t & 63, q = lane >> 4, nl = lane & 15;
    f32x4 acc[4][4];
#pragma unroll
    for (int i = 0; i < 4; ++i)
#pragma unroll
        for (int j = 0; j < 4; ++j)
            acc[i][j] = (f32x4){0.f, 0.f, 0.f, 0.f};
    for (int k0 = 0; k0 < K; k0 += 32) {
        __syncthreads();
#pragma unroll
        for (int it = 0; it < 4; ++it) {
            int idx = t + it * 256;
            int pr = idx >> 2, kq = idx & 3;
            uint4 v = *(const uint4*)&X[(size_t)(P0 + pr) * K + k0 + kq * 8];
            *(uint4*)&a_sh[pr * 40 + kq * 8] = v;
        }
#pragma unroll
        for (int it = 0; it < 2; ++it) {
            int idx = t + it * 256;
            int nr = idx >> 3, kq = idx & 7;
            int ng = N0 + nr; if (ng > N - 1) ng = N - 1;
            float4 v = *(const float4*)&W[(size_t)ng * K + k0 + kq * 4];
            ushort4 u;
            u.x = f2bu(v.x); u.y = f2bu(v.y); u.z = f2bu(v.z); u.w = f2bu(v.w);
            *(ushort4*)&b_sh[nr * 40 + kq * 4] = u;
        }
        __syncthreads();
        bf16x8 af[4], bfr[4];
#pragma unroll
        for (int mf = 0; mf < 4; ++mf)
            af[mf] = *(const bf16x8*)&a_sh[(w * 64 + mf * 16 + nl) * 40 + q * 8];
#pragma unroll
        for (int nf = 0; nf < 4; ++nf)
            bfr[nf] = *(const bf16x8*)&b_sh[(nf * 16 + nl) * 40 + q * 8];
#pragma unroll
        for (int mf = 0; mf < 4; ++mf)
#pragma unroll
            for (int nf = 0; nf < 4; ++nf)
                acc[mf][nf] = __builtin_amdgcn_mfma_f32_16x16x32_bf16(
                    af[mf], bfr[nf], acc[mf][nf], 0, 0, 0);
    }
#pragma unroll
    for (int mf = 0; mf < 4; ++mf) {
#pragma unroll
        for (int nf = 0; nf < 4; ++nf) {
#pragma unroll
            for (int r = 0; r < 4; ++r) {
                float v = acc[mf][nf][r];
                size_t pos = (size_t)P0 + w * 64 + mf * 16 + q * 4 + r;
                int n = N0 + nf * 16 + nl;
                if constexpr (EPI == 0) {
                    unsigned short* xc = (unsigned short*)out0v;
                    unsigned short* zz = (unsigned short*)out1v;
                    if (n < 192) xc[pos * 192 + n] = f2bu(v);
                    else         zz[pos * 192 + (n - 192)] = f2bu(v);
                } else if constexpr (EPI == 1) {
                    if (n < 152) ((float*)out0v)[pos * 152 + n] = v;
                } else if constexpr (EPI == 2) {
                    if (n < 96) ((float*)out0v)[pos * 96 + n] = res[pos * 96 + n] + v;
                } else if constexpr (EPI == 3) {
                    ((unsigned short*)out0v)[pos * 384 + n] = f2bu(geluf(v + bias[n]));
                } else {
                    if (n < 96) ((float*)out0v)[pos * 96 + n] =
                        res[pos * 96 + n] + bias[n] + v;
                }
            }
        }
    }
}

// ---- K2: depthwise 3x3 conv + bias + silu, 2 channels/thread ---------------
__global__ __launch_bounds__(256) void k2_conv(
    const unsigned short* __restrict__ xcpre, const float* __restrict__ cw,
    const float* __restrict__ cb, unsigned short* __restrict__ xconv) {
    int idx = blockIdx.x * 256 + threadIdx.x;
    int dd = idx % 96;
    int P = idx / 96;
    int d0 = dd * 2;
    int b = P / LLEN, l = P - b * LLEN;
    int h = l / WWW, w = l - h * WWW;
    float acc0 = cb[d0], acc1 = cb[d0 + 1];
#pragma unroll
    for (int i = 0; i < 3; ++i) {
        int hh = h + i - 1;
        if (hh < 0 || hh >= HHH) continue;
#pragma unroll
        for (int j = 0; j < 3; ++j) {
            int ww = w + j - 1;
            if (ww < 0 || ww >= WWW) continue;
            ushort2 xv = *(const ushort2*)&xcpre[
                ((size_t)(b * LLEN + hh * WWW + ww)) * DIN + d0];
            union { unsigned short u; bf16 h_; } c0, c1;
            c0.u = xv.x; c1.u = xv.y;
            acc0 = fmaf(b2f(c0.h_), cw[d0 * 9 + i * 3 + j], acc0);
            acc1 = fmaf(b2f(c1.h_), cw[(d0 + 1) * 9 + i * 3 + j], acc1);
        }
    }
    acc0 = acc0 * sigm(acc0);
    acc1 = acc1 * sigm(acc1);
    ushort2 o; o.x = f2bu(acc0); o.y = f2bu(acc1);
    *(ushort2*)&xconv[(size_t)P * DIN + d0] = o;
}

// ---- K4: scan pass 1 — two segments per block, local h_end & sum(dt) -------
__global__ __launch_bounds__(192) void k4_scan1(
    const bf16* __restrict__ xconv, const float* __restrict__ proj,
    const float* __restrict__ dtw, const float* __restrict__ dtb,
    const float* __restrict__ Alog, float* __restrict__ hloc,
    float* __restrict__ tsum) {
    __shared__ float pl[98 * PJS1];
    __shared__ int posl[98];
    const int bid = blockIdx.x;              // 1024 = 8b * 4k * 32s2
    const int s2 = bid & 31, k = (bid >> 5) & 3, b = bid >> 7;
    const int d = threadIdx.x;
    const int l0 = s2 * (2 * SEGL);          // segA rows 0-48, segB rows 49-97
    for (int q = d; q < 98 * 22; q += 192) {
        int st = q / 22, c = q - st * 22;
        int p = pos_map(k, l0 + st);
        int ofs = (c < 6) ? c : c + 2;
        pl[st * PJS1 + ofs] = proj[(size_t)(b * LLEN + p) * PJW + k * PJC + c];
    }
    if (d < 98) posl[d] = pos_map(k, l0 + d) * DIN;
    float w6[RDT];
#pragma unroll
    for (int r = 0; r < RDT; ++r) w6[r] = dtw[(k * DIN + d) * RDT + r];
    const float bias = dtb[k * DIN + d];
    float a2[NST];
#pragma unroll
    for (int n = 0; n < NST; ++n)
        a2[n] = -__expf(Alog[(k * DIN + d) * NST + n]) * LOG2E;
    float hA[NST], hB[NST];
#pragma unroll
    for (int n = 0; n < NST; ++n) { hA[n] = 0.f; hB[n] = 0.f; }
    float TA = 0.f, TB = 0.f;
    __syncthreads();
    const bf16* xg = xconv + (size_t)b * LLEN * DIN + d;
    for (int bt = 0; bt < 7; ++bt) {
        int offA[7], offB[7]; float xvA[7], xvB[7];
#pragma unroll
        for (int i = 0; i < 7; ++i) { offA[i] = posl[bt * 7 + i]; offB[i] = posl[49 + bt * 7 + i]; }
#pragma unroll
        for (int i = 0; i < 7; ++i) { xvA[i] = b2f(xg[offA[i]]); xvB[i] = b2f(xg[offB[i]]); }
#pragma unroll
        for (int i = 0; i < 7; ++i) {
            const float* rA = &pl[(bt * 7 + i) * PJS1];
            const float* rB = &pl[(49 + bt * 7 + i) * PJS1];
            float4 gA0 = *(const float4*)(rA); float2 gA1 = *(const float2*)(rA + 4);
            float4 gB0 = *(const float4*)(rB); float2 gB1 = *(const float2*)(rB + 4);
            float dA = bias, dB = bias;
            dA = fmaf(gA0.x, w6[0], dA); dB = fmaf(gB0.x, w6[0], dB);
            dA = fmaf(gA0.y, w6[1], dA); dB = fmaf(gB0.y, w6[1], dB);
            dA = fmaf(gA0.z, w6[2], dA); dB = fmaf(gB0.z, w6[2], dB);
            dA = fmaf(gA0.w, w6[3], dA); dB = fmaf(gB0.w, w6[3], dB);
            dA = fmaf(gA1.x, w6[4], dA); dB = fmaf(gB1.x, w6[4], dB);
            dA = fmaf(gA1.y, w6[5], dA); dB = fmaf(gB1.y, w6[5], dB);
            dA = softplusf(dA); dB = softplusf(dB);
            TA += dA; TB += dB;
            float uA = dA * xvA[i], uB = dB * xvB[i];
#pragma unroll
            for (int g = 0; g < 4; ++g) {
                float4 BA = *(const float4*)(rA + 8 + 4 * g);
                float4 BB = *(const float4*)(rB + 8 + 4 * g);
#pragma unroll
                for (int m = 0; m < 4; ++m) {
                    int n = 4 * g + m;
                    float Bae = (m == 0) ? BA.x : (m == 1) ? BA.y : (m == 2) ? BA.z : BA.w;
                    float Bbe = (m == 0) ? BB.x : (m == 1) ? BB.y : (m == 2) ? BB.z : BB.w;
                    float eA = EXP2F(dA * a2[n]);
                    float eB = EXP2F(dB * a2[n]);
                    hA[n] = fmaf(hA[n], eA, uA * Bae);
                    hB[n] = fmaf(hB[n], eB, uB * Bbe);
                }
            }
        }
    }
    const int bk = b * KDIR + k;
    size_t baseA = ((size_t)(bk * SSEG + 2 * s2) * DIN + d) * NST;
    size_t baseB = ((size_t)(bk * SSEG + 2 * s2 + 1) * DIN + d) * NST;
#pragma unroll
    for (int n = 0; n < NST; ++n) { hloc[baseA + n] = hA[n]; hloc[baseB + n] = hB[n]; }
    tsum[(bk * SSEG + 2 * s2) * DIN + d] = TA;
    tsum[(bk * SSEG + 2 * s2 + 1) * DIN + d] = TB;
}

// ---- K5: exact segment carries (hin aliases hloc: read-before-write) -------
__global__ __launch_bounds__(256) void k5_carry(
    const float* hloc, const float* __restrict__ tsum,
    const float* __restrict__ Alog, float* hin) {
    int g = blockIdx.x * 256 + threadIdx.x;   // over B*K*D*N
    int n = g & 15;
    int dk = g >> 4;
    int d = dk % DIN;
    int bk = dk / DIN;                        // b*4 + k
    int k = bk & 3;
    float a2 = -__expf(Alog[(k * DIN + d) * NST + n]) * LOG2E;
    float Hc = 0.f;
    for (int s = 0; s < SSEG; ++s) {
        int bid = bk * SSEG + s;
        size_t idx = ((size_t)bid * DIN + d) * NST + n;
        float hl = hloc[idx];
        float Tv = tsum[bid * DIN + d];
        hin[idx] = Hc;
        Hc = fmaf(EXP2F(a2 * Tv), Hc, hl);
    }
}

// ---- K6: scan pass 2 — two segments per block, exact from carries ----------
__global__ __launch_bounds__(192) void k6_scan2(
    const bf16* __restrict__ xconv, const float* __restrict__ proj,
    const float* __restrict__ dtw, const float* __restrict__ dtb,
    const float* __restrict__ Alog, const float* __restrict__ Dsp,
    const float* __restrict__ hin, bf16* __restrict__ ysm) {
    __shared__ float pl[98 * PJS];
    __shared__ int posl[98];
    const int bid = blockIdx.x;
    const int s2 = bid & 31, k = (bid >> 5) & 3, b = bid >> 7;
    const int d = threadIdx.x;
    const int l0 = s2 * (2 * SEGL);
    for (int q = d; q < 98 * PJC; q += 192) {
        int st = q / PJC, c = q - st * PJC;
        int p = pos_map(k, l0 + st);
        int ofs = (c < 6) ? c : c + 2;
        pl[st * PJS + ofs] = proj[(size_t)(b * LLEN + p) * PJW + k * PJC + c];
    }
    if (d < 98) posl[d] = pos_map(k, l0 + d) * DIN;
    float w6[RDT];
#pragma unroll
    for (int r = 0; r < RDT; ++r) w6[r] = dtw[(k * DIN + d) * RDT + r];
    const float bias = dtb[k * DIN + d];
    const float dsv = Dsp[k * DIN + d];
    float a2[NST];
#pragma unroll
    for (int n = 0; n < NST; ++n)
        a2[n] = -__expf(Alog[(k * DIN + d) * NST + n]) * LOG2E;
    const int bk = b * KDIR + k;
    float hA[NST], hB[NST];
    size_t hbA = ((size_t)(bk * SSEG + 2 * s2) * DIN + d) * NST;
    size_t hbB = ((size_t)(bk * SSEG + 2 * s2 + 1) * DIN + d) * NST;
#pragma unroll
    for (int n = 0; n < NST; ++n) { hA[n] = hin[hbA + n]; hB[n] = hin[hbB + n]; }
    __syncthreads();
    const bf16* xg = xconv + (size_t)b * LLEN * DIN + d;
    bf16* ysg = ysm + ((size_t)bk * LLEN) * DIN + d;
    for (int bt = 0; bt < 7; ++bt) {
        int offA[7], offB[7]; float xvA[7], xvB[7];
#pragma unroll
        for (int i = 0; i < 7; ++i) { offA[i] = posl[bt * 7 + i]; offB[i] = posl[49 + bt * 7 + i]; }
#pragma unroll
        for (int i = 0; i < 7; ++i) { xvA[i] = b2f(xg[offA[i]]); xvB[i] = b2f(xg[offB[i]]); }
#pragma unroll
        for (int i = 0; i < 7; ++i) {
            const float* rA = &pl[(bt * 7 + i) * PJS];
            const float* rB = &pl[(49 + bt * 7 + i) * PJS];
            float4 gA0 = *(const float4*)(rA); float2 gA1 = *(const float2*)(rA + 4);
            float4 gB0 = *(const float4*)(rB); float2 gB1 = *(const float2*)(rB + 4);
            float dA = bias, dB = bias;
            dA = fmaf(gA0.x, w6[0], dA); dB = fmaf(gB0.x, w6[0], dB);
            dA = fmaf(gA0.y, w6[1], dA); dB = fmaf(gB0.y, w6[1], dB);
            dA = fmaf(gA0.z, w6[2], dA); dB = fmaf(gB0.z, w6[2], dB);
            dA = fmaf(gA0.w, w6[3], dA); dB = fmaf(gB0.w, w6[3], dB);
            dA = fmaf(gA1.x, w6[4], dA); dB = fmaf(gB1.x, w6[4], dB);
            dA = fmaf(gA1.y, w6[5], dA); dB = fmaf(gB1.y, w6[5], dB);
            dA = softplusf(dA); dB = softplusf(dB);
            float uA = dA * xvA[i], uB = dB * xvB[i];
            float yA = dsv * xvA[i], yB = dsv * xvB[i];
#pragma unroll
            for (int g = 0; g < 4; ++g) {
                float4 BA = *(const float4*)(rA + 8 + 4 * g);
                float4 CA = *(const float4*)(rA + 24 + 4 * g);
                float4 BB = *(const float4*)(rB + 8 + 4 * g);
                float4 CB = *(const float4*)(rB + 24 + 4 * g);
#pragma unroll
                for (int m = 0; m < 4; ++m) {
                    int n = 4 * g + m;
                    float Bae = (m == 0) ? BA.x : (m == 1) ? BA.y : (m == 2) ? BA.z : BA.w;
                    float Cae = (m == 0) ? CA.x : (m == 1) ? CA.y : (m == 2) ? CA.z : CA.w;
                    float Bbe = (m == 0) ? BB.x : (m == 1) ? BB.y : (m == 2) ? BB.z : BB.w;
                    float Cbe = (m == 0) ? CB.x : (m == 1) ? CB.y : (m == 2) ? CB.z : CB.w;
                    float eA = EXP2F(dA * a2[n]);
                    float eB = EXP2F(dB * a2[n]);
                    hA[n] = fmaf(hA[n], eA, uA * Bae);
                    hB[n] = fmaf(hB[n], eB, uB * Bbe);
                    yA = fmaf(hA[n], Cae, yA);
                    yB = fmaf(hB[n], Cbe, yB);
                }
            }
            ysg[offA[i]] = f2b(yA);
            ysg[offB[i]] = f2b(yB);
        }
    }
}

// ---- K6.5: merge 4 planes + out_norm LN + *silu(z) -------------------------
__global__ __launch_bounds__(256) void k65_merge(
    const bf16* __restrict__ ysm, const bf16* __restrict__ z,
    const float* __restrict__ onw, const float* __restrict__ onb,
    bf16* __restrict__ ymod) {
    __shared__ float rb[16 * DIN];
    __shared__ float ps[256], pq[256];
    __shared__ float mrow[16], srow[16];
    const int t = threadIdx.x;
    const int P0 = blockIdx.x * 16;
    for (int q = t; q < 16 * DIN; q += 256) {
        int pos = q / DIN, c = q - pos * DIN;
        int P = P0 + pos;
        int b = P / LLEN, l = P - b * LLEN;
        size_t base = ((size_t)(b * KDIR) * LLEN + l) * DIN + c;
        size_t pstr = (size_t)LLEN * DIN;
        float v = b2f(ysm[base]) + b2f(ysm[base + pstr]) +
                  b2f(ysm[base + 2 * pstr]) + b2f(ysm[base + 3 * pstr]);
        rb[q] = v;
    }
    __syncthreads();
    {
        int pos = t >> 4, part = t & 15;
        float s = 0.f, s2 = 0.f;
        for (int i = 0; i < 12; ++i) {
            float v = rb[pos * DIN + part * 12 + i];
            s += v; s2 += v * v;
        }
        ps[pos * 16 + part] = s; pq[pos * 16 + part] = s2;
    }
    __syncthreads();
    if (t < 16) {
        float s = 0.f, s2 = 0.f;
        for (int i = 0; i < 16; ++i) { s += ps[t * 16 + i]; s2 += pq[t * 16 + i]; }
        float m = s * (1.f / DIN);
        float v = s2 * (1.f / DIN) - m * m;
        mrow[t] = m; srow[t] = rsqrtf(v + 1e-5f);
    }
    __syncthreads();
    for (int q = t; q < 16 * DIN; q += 256) {
        int pos = q / DIN, c = q - pos * DIN;
        int P = P0 + pos;
        float v = (rb[q] - mrow[pos]) * srow[pos] * onw[c] + onb[c];
        float zv = b2f(z[(size_t)P * DIN + c]);
        v *= zv * sigm(zv);
        ymod[(size_t)P * DIN + c] = f2b(v);
    }
}

extern "C" void kernel_launch(void* const* d_in, const int* in_sizes, int n_in,
                              void* d_out, int out_size, void* d_ws, size_t ws_size,
                              hipStream_t stream) {
    const float* x      = (const float*)d_in[0];
    const float* ln1w   = (const float*)d_in[1];
    const float* ln1b   = (const float*)d_in[2];
    const float* inpW   = (const float*)d_in[3];
    const float* convW  = (const float*)d_in[4];
    const float* convB  = (const float*)d_in[5];
    const float* xprojW = (const float*)d_in[6];
    const float* dtW    = (const float*)d_in[7];
    const float* dtB    = (const float*)d_in[8];
    const float* Alog   = (const float*)d_in[9];
    const float* Dsp    = (const float*)d_in[10];
    const float* onw    = (const float*)d_in[11];
    const float* onb    = (const float*)d_in[12];
    const float* outW   = (const float*)d_in[13];
    const float* ln2w   = (const float*)d_in[14];
    const float* ln2b   = (const float*)d_in[15];
    const float* fc1W   = (const float*)d_in[16];
    const float* fc1b   = (const float*)d_in[17];
    const float* fc2W   = (const float*)d_in[18];
    const float* fc2b   = (const float*)d_in[19];
    float* out = (float*)d_out;

    char* ws = (char*)d_ws;
    unsigned short* z_us    = (unsigned short*)(ws + 0);           // [G1..k65]
    bf16*  z_bf             = (bf16*)z_us;
    bf16*  xconv_bf         = (bf16*)(ws + 9633792);               // [k2..k6]
    float* proj_f           = (float*)(ws + 19267584);             // [G2..k6]
    bf16*  ymod_bf          = (bf16*)(ws + 19267584);              // [k65..G3]
    unsigned short* xn_us   = (unsigned short*)(ws + 34521088);    // [LN1..G1]
    float* tsum_f           = (float*)(ws + 34521088);             // [k4..k6]
    unsigned short* xcpre_us= (unsigned short*)(ws + 39337984);    // [G1..k2]
    float* hloc_f           = (float*)(ws + 48971776);             // [k4..k6]
    float* hin_f            = hloc_f;                              // k5 r-b-w alias
    float* y1_f             = (float*)(ws + 48971776);             // [G3..G5]
    unsigned short* y1n_us  = (unsigned short*)(ws + 58605568);    // [LN2..G4]
    bf16*  ysm_bf           = (bf16*)(ws + 74137600);              // [k6..k65]
    unsigned short* hmlp_us = (unsigned short*)(ws + 74137600);    // [G4..G5]

    ln_rows<<<6272, 256, 0, stream>>>(x, ln1w, ln1b, xn_us);
    gemm_mfma<384, 96, 0><<<dim3(98, 6), 256, 0, stream>>>(
        xn_us, inpW, nullptr, nullptr, xcpre_us, z_us);
    k2_conv<<<9408, 256, 0, stream>>>(xcpre_us, convW, convB,
                                      (unsigned short*)xconv_bf);
    gemm_mfma<152, 192, 1><<<dim3(98, 3), 256, 0, stream>>>(
        (const unsigned short*)xconv_bf, xprojW, nullptr, nullptr, proj_f, nullptr);
    k4_scan1<<<1024, 192, 0, stream>>>(xconv_bf, proj_f, dtW, dtB, Alog, hloc_f, tsum_f);
    k5_carry<<<384, 256, 0, stream>>>(hloc_f, tsum_f, Alog, hin_f);
    k6_scan2<<<1024, 192, 0, stream>>>(xconv_bf, proj_f, dtW, dtB, Alog, Dsp, hin_f, ysm_bf);
    k65_merge<<<1568, 256, 0, stream>>>(ysm_bf, z_bf, onw, onb, ymod_bf);
    gemm_mfma<96, 192, 2><<<dim3(98, 2), 256, 0, stream>>>(
        (const unsigned short*)ymod_bf, outW, nullptr, x, y1_f, nullptr);
    ln_rows<<<6272, 256, 0, stream>>>(y1_f, ln2w, ln2b, y1n_us);
    gemm_mfma<384, 96, 3><<<dim3(98, 6), 256, 0, stream>>>(
        y1n_us, fc1W, fc1b, nullptr, hmlp_us, nullptr);
    gemm_mfma<96, 384, 4><<<dim3(98, 2), 256, 0, stream>>>(
        hmlp_us, fc2W, fc2b, y1_f, out, nullptr);
}

// Round 5
// 396.561 us; speedup vs baseline: 1.1059x; 1.1059x over previous
//
#include <hip/hip_runtime.h>
#include <hip/hip_bf16.h>

typedef __hip_bfloat16 bf16;
typedef short bf16x8 __attribute__((ext_vector_type(8)));
typedef float f32x4 __attribute__((ext_vector_type(4)));

#define BBATCH 8
#define HHH 56
#define WWW 56
#define CCH 96          // C
#define DIN 192         // D
#define NST 16          // N
#define KDIR 4          // K
#define RDT 6           // R
#define LLEN 3136       // H*W
#define BLTOT 25088     // B*L
#define SSEG 64         // segments
#define SEGL 49         // L / SSEG
#define PJC 38          // R + 2N
#define PJW 152         // K * PJC
#define PJS 40          // padded LDS row stride (16B aligned)
#define PJS1 24         // pass-1 padded row stride (r+B only)
#define MLPH 384

// native exp2/log2 (v_exp_f32 / v_log_f32) with safe fallbacks
#if defined(__has_builtin)
#if __has_builtin(__builtin_amdgcn_exp2f)
#define EXP2F(x) __builtin_amdgcn_exp2f(x)
#endif
#if __has_builtin(__builtin_amdgcn_logf)
#define LOG2F_(x) __builtin_amdgcn_logf(x)
#endif
#endif
#ifndef EXP2F
#define EXP2F(x) __expf((x) * 0.69314718056f)
#endif
#ifndef LOG2F_
#define LOG2F_(x) (__logf(x) * 1.44269504f)
#endif
#define LOG2E 1.44269504f

__device__ __forceinline__ float b2f(bf16 v) { return __bfloat162float(v); }
__device__ __forceinline__ bf16  f2b(float v) { return __float2bfloat16(v); }
__device__ __forceinline__ unsigned short f2bu(float f) {
    union { bf16 h; unsigned short u; } c; c.h = __float2bfloat16(f); return c.u;
}
__device__ __forceinline__ float sigm(float x) { return 1.f / (1.f + __expf(-x)); }
__device__ __forceinline__ float softplusf(float x) {
    float t = EXP2F(-fabsf(x) * LOG2E);
    return fmaxf(x, 0.f) + 0.69314718f * LOG2F_(1.f + t);
}
__device__ __forceinline__ float geluf(float v) {
    float u = 0.7978845608028654f * (v + 0.044715f * v * v * v);
    float ey = __expf(2.f * u);
    float th = 1.f - 2.f / (ey + 1.f);
    return 0.5f * v * (1.f + th);
}

// scan-step l -> spatial position (row-major h*56+w) for direction k
__device__ __forceinline__ int pos_map(int k, int l) {
    if (k & 2) l = LLEN - 1 - l;
    if (k & 1) { int q = l / WWW; int r = l - q * WWW; return r * WWW + q; }
    return l;
}

// ---- LN: one wave per row of 96, emit bf16 ---------------------------------
__global__ __launch_bounds__(256) void ln_rows(
    const float* __restrict__ xin, const float* __restrict__ w,
    const float* __restrict__ b, unsigned short* __restrict__ xn) {
    int row = blockIdx.x * 4 + (threadIdx.x >> 6);
    int lane = threadIdx.x & 63;
    const float* xr = xin + (size_t)row * 96;
    float2 v = make_float2(0.f, 0.f);
    if (lane < 48) v = *(const float2*)&xr[lane * 2];
    float s = v.x + v.y, s2 = v.x * v.x + v.y * v.y;
    for (int o = 32; o; o >>= 1) {
        s += __shfl_down(s, o);
        s2 += __shfl_down(s2, o);
    }
    s = __shfl(s, 0); s2 = __shfl(s2, 0);
    float m = s * (1.f / 96.f);
    float var = s2 * (1.f / 96.f) - m * m;
    float rs = rsqrtf(var + 1e-5f);
    if (lane < 48) {
        float o0 = (v.x - m) * rs * w[lane * 2] + b[lane * 2];
        float o1 = (v.y - m) * rs * w[lane * 2 + 1] + b[lane * 2 + 1];
        ushort2 u; u.x = f2bu(o0); u.y = f2bu(o1);
        *(ushort2*)&xn[(size_t)row * 96 + lane * 2] = u;
    }
}

// ---- Unified MFMA GEMM: C[M=25088][N] = X[M][K](bf16) . W[N][K]^T(f32) -----
// block: 4 waves, each wave one 64-row M-strip, 4x4 frags -> 256M x 64N tile.
// EPI: 0=split xc/z  1=proj f32  2=+res f32  3=gelu(+bias) bf16  4=+bias+res f32
template<int N, int K, int EPI>
__global__ __launch_bounds__(256) void gemm_mfma(
    const unsigned short* __restrict__ X, const float* __restrict__ W,
    const float* __restrict__ bias, const float* __restrict__ res,
    void* __restrict__ out0v, void* __restrict__ out1v) {
    __shared__ unsigned short a_sh[256 * 40];
    __shared__ unsigned short b_sh[64 * 40];
    const int t = threadIdx.x;
    const int P0 = blockIdx.x * 256;
    const int N0 = blockIdx.y * 64;
    const int w = t >> 6, lane = t & 63, q = lane >> 4, nl = lane & 15;
    f32x4 acc[4][4];
#pragma unroll
    for (int i = 0; i < 4; ++i)
#pragma unroll
        for (int j = 0; j < 4; ++j)
            acc[i][j] = (f32x4){0.f, 0.f, 0.f, 0.f};
    for (int k0 = 0; k0 < K; k0 += 32) {
        __syncthreads();
#pragma unroll
        for (int it = 0; it < 4; ++it) {
            int idx = t + it * 256;
            int pr = idx >> 2, kq = idx & 3;
            uint4 v = *(const uint4*)&X[(size_t)(P0 + pr) * K + k0 + kq * 8];
            *(uint4*)&a_sh[pr * 40 + kq * 8] = v;
        }
#pragma unroll
        for (int it = 0; it < 2; ++it) {
            int idx = t + it * 256;
            int nr = idx >> 3, kq = idx & 7;
            int ng = N0 + nr; if (ng > N - 1) ng = N - 1;
            float4 v = *(const float4*)&W[(size_t)ng * K + k0 + kq * 4];
            ushort4 u;
            u.x = f2bu(v.x); u.y = f2bu(v.y); u.z = f2bu(v.z); u.w = f2bu(v.w);
            *(ushort4*)&b_sh[nr * 40 + kq * 4] = u;
        }
        __syncthreads();
        bf16x8 af[4], bfr[4];
#pragma unroll
        for (int mf = 0; mf < 4; ++mf)
            af[mf] = *(const bf16x8*)&a_sh[(w * 64 + mf * 16 + nl) * 40 + q * 8];
#pragma unroll
        for (int nf = 0; nf < 4; ++nf)
            bfr[nf] = *(const bf16x8*)&b_sh[(nf * 16 + nl) * 40 + q * 8];
#pragma unroll
        for (int mf = 0; mf < 4; ++mf)
#pragma unroll
            for (int nf = 0; nf < 4; ++nf)
                acc[mf][nf] = __builtin_amdgcn_mfma_f32_16x16x32_bf16(
                    af[mf], bfr[nf], acc[mf][nf], 0, 0, 0);
    }
#pragma unroll
    for (int mf = 0; mf < 4; ++mf) {
#pragma unroll
        for (int nf = 0; nf < 4; ++nf) {
#pragma unroll
            for (int r = 0; r < 4; ++r) {
                float v = acc[mf][nf][r];
                size_t pos = (size_t)P0 + w * 64 + mf * 16 + q * 4 + r;
                int n = N0 + nf * 16 + nl;
                if constexpr (EPI == 0) {
                    unsigned short* xc = (unsigned short*)out0v;
                    unsigned short* zz = (unsigned short*)out1v;
                    if (n < 192) xc[pos * 192 + n] = f2bu(v);
                    else         zz[pos * 192 + (n - 192)] = f2bu(v);
                } else if constexpr (EPI == 1) {
                    if (n < 152) ((float*)out0v)[pos * 152 + n] = v;
                } else if constexpr (EPI == 2) {
                    if (n < 96) ((float*)out0v)[pos * 96 + n] = res[pos * 96 + n] + v;
                } else if constexpr (EPI == 3) {
                    ((unsigned short*)out0v)[pos * 384 + n] = f2bu(geluf(v + bias[n]));
                } else {
                    if (n < 96) ((float*)out0v)[pos * 96 + n] =
                        res[pos * 96 + n] + bias[n] + v;
                }
            }
        }
    }
}

// ---- K2: depthwise 3x3 conv + bias + silu, 2 channels/thread ---------------
__global__ __launch_bounds__(256) void k2_conv(
    const unsigned short* __restrict__ xcpre, const float* __restrict__ cw,
    const float* __restrict__ cb, unsigned short* __restrict__ xconv) {
    int idx = blockIdx.x * 256 + threadIdx.x;
    int dd = idx % 96;
    int P = idx / 96;
    int d0 = dd * 2;
    int b = P / LLEN, l = P - b * LLEN;
    int h = l / WWW, w = l - h * WWW;
    float acc0 = cb[d0], acc1 = cb[d0 + 1];
#pragma unroll
    for (int i = 0; i < 3; ++i) {
        int hh = h + i - 1;
        if (hh < 0 || hh >= HHH) continue;
#pragma unroll
        for (int j = 0; j < 3; ++j) {
            int ww = w + j - 1;
            if (ww < 0 || ww >= WWW) continue;
            ushort2 xv = *(const ushort2*)&xcpre[
                ((size_t)(b * LLEN + hh * WWW + ww)) * DIN + d0];
            union { unsigned short u; bf16 h_; } c0, c1;
            c0.u = xv.x; c1.u = xv.y;
            acc0 = fmaf(b2f(c0.h_), cw[d0 * 9 + i * 3 + j], acc0);
            acc1 = fmaf(b2f(c1.h_), cw[(d0 + 1) * 9 + i * 3 + j], acc1);
        }
    }
    acc0 = acc0 * sigm(acc0);
    acc1 = acc1 * sigm(acc1);
    ushort2 o; o.x = f2bu(acc0); o.y = f2bu(acc1);
    *(ushort2*)&xconv[(size_t)P * DIN + d0] = o;
}

// ---- K4: scan pass 1 — one segment per block, local h_end & sum(dt) --------
__global__ __launch_bounds__(192) void k4_scan1(
    const bf16* __restrict__ xconv, const float* __restrict__ proj,
    const float* __restrict__ dtw, const float* __restrict__ dtb,
    const float* __restrict__ Alog, float* __restrict__ hloc,
    float* __restrict__ tsum) {
    __shared__ float pl[SEGL * PJS1];
    __shared__ int posl[SEGL];
    const int bid = blockIdx.x;              // 2048 = 8b * 4k * 64s
    const int s = bid & 63, k = (bid >> 6) & 3, b = bid >> 8;
    const int d = threadIdx.x;
    const int l0 = s * SEGL;
    for (int q = d; q < SEGL * 22; q += 192) {
        int st = q / 22, c = q - st * 22;
        int p = pos_map(k, l0 + st);
        int ofs = (c < 6) ? c : c + 2;
        pl[st * PJS1 + ofs] = proj[(size_t)(b * LLEN + p) * PJW + k * PJC + c];
    }
    if (d < SEGL) posl[d] = pos_map(k, l0 + d) * DIN;
    float w6[RDT];
#pragma unroll
    for (int r = 0; r < RDT; ++r) w6[r] = dtw[(k * DIN + d) * RDT + r];
    const float bias = dtb[k * DIN + d];
    float a2[NST];
#pragma unroll
    for (int n = 0; n < NST; ++n)
        a2[n] = -__expf(Alog[(k * DIN + d) * NST + n]) * LOG2E;
    float h[NST];
#pragma unroll
    for (int n = 0; n < NST; ++n) h[n] = 0.f;
    float T = 0.f;
    __syncthreads();
    const bf16* xg = xconv + (size_t)b * LLEN * DIN + d;
    for (int bt = 0; bt < 7; ++bt) {
        int off7[7]; float xv7[7];
#pragma unroll
        for (int i = 0; i < 7; ++i) off7[i] = posl[bt * 7 + i];
#pragma unroll
        for (int i = 0; i < 7; ++i) xv7[i] = b2f(xg[off7[i]]);
#pragma unroll
        for (int i = 0; i < 7; ++i) {
            const float* rowf = &pl[(bt * 7 + i) * PJS1];
            float4 g0 = *(const float4*)(rowf);
            float2 g1 = *(const float2*)(rowf + 4);
            float dtv = bias;
            dtv = fmaf(g0.x, w6[0], dtv); dtv = fmaf(g0.y, w6[1], dtv);
            dtv = fmaf(g0.z, w6[2], dtv); dtv = fmaf(g0.w, w6[3], dtv);
            dtv = fmaf(g1.x, w6[4], dtv); dtv = fmaf(g1.y, w6[5], dtv);
            dtv = softplusf(dtv);
            T += dtv;
            float u = dtv * xv7[i];
#pragma unroll
            for (int g = 0; g < 4; ++g) {
                float4 Bv = *(const float4*)(rowf + 8 + 4 * g);
                float e0 = EXP2F(dtv * a2[4 * g + 0]);
                float e1 = EXP2F(dtv * a2[4 * g + 1]);
                float e2 = EXP2F(dtv * a2[4 * g + 2]);
                float e3 = EXP2F(dtv * a2[4 * g + 3]);
                h[4 * g + 0] = fmaf(h[4 * g + 0], e0, u * Bv.x);
                h[4 * g + 1] = fmaf(h[4 * g + 1], e1, u * Bv.y);
                h[4 * g + 2] = fmaf(h[4 * g + 2], e2, u * Bv.z);
                h[4 * g + 3] = fmaf(h[4 * g + 3], e3, u * Bv.w);
            }
        }
    }
    size_t base = ((size_t)bid * DIN + d) * NST;
#pragma unroll
    for (int n = 0; n < NST; ++n) hloc[base + n] = h[n];
    tsum[bid * DIN + d] = T;
}

// ---- K5: exact segment carries (hin aliases hloc: read-before-write) -------
__global__ __launch_bounds__(256) void k5_carry(
    const float* hloc, const float* __restrict__ tsum,
    const float* __restrict__ Alog, float* hin) {
    int g = blockIdx.x * 256 + threadIdx.x;   // over B*K*D*N
    int n = g & 15;
    int dk = g >> 4;
    int d = dk % DIN;
    int bk = dk / DIN;                        // b*4 + k
    int k = bk & 3;
    float a2 = -__expf(Alog[(k * DIN + d) * NST + n]) * LOG2E;
    float Hc = 0.f;
    for (int s = 0; s < SSEG; ++s) {
        int bid = bk * SSEG + s;
        size_t idx = ((size_t)bid * DIN + d) * NST + n;
        float hl = hloc[idx];
        float Tv = tsum[bid * DIN + d];
        hin[idx] = Hc;
        Hc = fmaf(EXP2F(a2 * Tv), Hc, hl);
    }
}

// ---- K6: scan pass 2 — one segment per block, exact from carries -----------
__global__ __launch_bounds__(192) void k6_scan2(
    const bf16* __restrict__ xconv, const float* __restrict__ proj,
    const float* __restrict__ dtw, const float* __restrict__ dtb,
    const float* __restrict__ Alog, const float* __restrict__ Dsp,
    const float* __restrict__ hin, bf16* __restrict__ ysm) {
    __shared__ float pl[SEGL * PJS];
    __shared__ int posl[SEGL];
    const int bid = blockIdx.x;
    const int s = bid & 63, k = (bid >> 6) & 3, b = bid >> 8;
    const int d = threadIdx.x;
    const int l0 = s * SEGL;
    for (int q = d; q < SEGL * PJC; q += 192) {
        int st = q / PJC, c = q - st * PJC;
        int p = pos_map(k, l0 + st);
        int ofs = (c < 6) ? c : c + 2;
        pl[st * PJS + ofs] = proj[(size_t)(b * LLEN + p) * PJW + k * PJC + c];
    }
    if (d < SEGL) posl[d] = pos_map(k, l0 + d) * DIN;
    float w6[RDT];
#pragma unroll
    for (int r = 0; r < RDT; ++r) w6[r] = dtw[(k * DIN + d) * RDT + r];
    const float bias = dtb[k * DIN + d];
    const float dsv = Dsp[k * DIN + d];
    float a2[NST];
#pragma unroll
    for (int n = 0; n < NST; ++n)
        a2[n] = -__expf(Alog[(k * DIN + d) * NST + n]) * LOG2E;
    float h[NST];
    size_t hbase = ((size_t)bid * DIN + d) * NST;
#pragma unroll
    for (int n = 0; n < NST; ++n) h[n] = hin[hbase + n];
    __syncthreads();
    const bf16* xg = xconv + (size_t)b * LLEN * DIN + d;
    bf16* ysg = ysm + ((size_t)(b * KDIR + k) * LLEN) * DIN + d;
    for (int bt = 0; bt < 7; ++bt) {
        int off7[7]; float xv7[7];
#pragma unroll
        for (int i = 0; i < 7; ++i) off7[i] = posl[bt * 7 + i];
#pragma unroll
        for (int i = 0; i < 7; ++i) xv7[i] = b2f(xg[off7[i]]);
#pragma unroll
        for (int i = 0; i < 7; ++i) {
            const float* rowf = &pl[(bt * 7 + i) * PJS];
            float4 g0 = *(const float4*)(rowf);
            float2 g1 = *(const float2*)(rowf + 4);
            float dtv = bias;
            dtv = fmaf(g0.x, w6[0], dtv); dtv = fmaf(g0.y, w6[1], dtv);
            dtv = fmaf(g0.z, w6[2], dtv); dtv = fmaf(g0.w, w6[3], dtv);
            dtv = fmaf(g1.x, w6[4], dtv); dtv = fmaf(g1.y, w6[5], dtv);
            dtv = softplusf(dtv);
            float u = dtv * xv7[i];
            float y = dsv * xv7[i];
#pragma unroll
            for (int g = 0; g < 4; ++g) {
                float4 Bv = *(const float4*)(rowf + 8 + 4 * g);
                float4 Cv = *(const float4*)(rowf + 24 + 4 * g);
                float e0 = EXP2F(dtv * a2[4 * g + 0]);
                float e1 = EXP2F(dtv * a2[4 * g + 1]);
                float e2 = EXP2F(dtv * a2[4 * g + 2]);
                float e3 = EXP2F(dtv * a2[4 * g + 3]);
                h[4 * g + 0] = fmaf(h[4 * g + 0], e0, u * Bv.x);
                h[4 * g + 1] = fmaf(h[4 * g + 1], e1, u * Bv.y);
                h[4 * g + 2] = fmaf(h[4 * g + 2], e2, u * Bv.z);
                h[4 * g + 3] = fmaf(h[4 * g + 3], e3, u * Bv.w);
                y = fmaf(h[4 * g + 0], Cv.x, y);
                y = fmaf(h[4 * g + 1], Cv.y, y);
                y = fmaf(h[4 * g + 2], Cv.z, y);
                y = fmaf(h[4 * g + 3], Cv.w, y);
            }
            ysg[off7[i]] = f2b(y);
        }
    }
}

// ---- K6.5: merge 4 planes + out_norm LN + *silu(z) -------------------------
__global__ __launch_bounds__(256) void k65_merge(
    const bf16* __restrict__ ysm, const bf16* __restrict__ z,
    const float* __restrict__ onw, const float* __restrict__ onb,
    bf16* __restrict__ ymod) {
    __shared__ float rb[16 * DIN];
    __shared__ float ps[256], pq[256];
    __shared__ float mrow[16], srow[16];
    const int t = threadIdx.x;
    const int P0 = blockIdx.x * 16;
    for (int q = t; q < 16 * DIN; q += 256) {
        int pos = q / DIN, c = q - pos * DIN;
        int P = P0 + pos;
        int b = P / LLEN, l = P - b * LLEN;
        size_t base = ((size_t)(b * KDIR) * LLEN + l) * DIN + c;
        size_t pstr = (size_t)LLEN * DIN;
        float v = b2f(ysm[base]) + b2f(ysm[base + pstr]) +
                  b2f(ysm[base + 2 * pstr]) + b2f(ysm[base + 3 * pstr]);
        rb[q] = v;
    }
    __syncthreads();
    {
        int pos = t >> 4, part = t & 15;
        float s = 0.f, s2 = 0.f;
        for (int i = 0; i < 12; ++i) {
            float v = rb[pos * DIN + part * 12 + i];
            s += v; s2 += v * v;
        }
        ps[pos * 16 + part] = s; pq[pos * 16 + part] = s2;
    }
    __syncthreads();
    if (t < 16) {
        float s = 0.f, s2 = 0.f;
        for (int i = 0; i < 16; ++i) { s += ps[t * 16 + i]; s2 += pq[t * 16 + i]; }
        float m = s * (1.f / DIN);
        float v = s2 * (1.f / DIN) - m * m;
        mrow[t] = m; srow[t] = rsqrtf(v + 1e-5f);
    }
    __syncthreads();
    for (int q = t; q < 16 * DIN; q += 256) {
        int pos = q / DIN, c = q - pos * DIN;
        int P = P0 + pos;
        float v = (rb[q] - mrow[pos]) * srow[pos] * onw[c] + onb[c];
        float zv = b2f(z[(size_t)P * DIN + c]);
        v *= zv * sigm(zv);
        ymod[(size_t)P * DIN + c] = f2b(v);
    }
}

extern "C" void kernel_launch(void* const* d_in, const int* in_sizes, int n_in,
                              void* d_out, int out_size, void* d_ws, size_t ws_size,
                              hipStream_t stream) {
    const float* x      = (const float*)d_in[0];
    const float* ln1w   = (const float*)d_in[1];
    const float* ln1b   = (const float*)d_in[2];
    const float* inpW   = (const float*)d_in[3];
    const float* convW  = (const float*)d_in[4];
    const float* convB  = (const float*)d_in[5];
    const float* xprojW = (const float*)d_in[6];
    const float* dtW    = (const float*)d_in[7];
    const float* dtB    = (const float*)d_in[8];
    const float* Alog   = (const float*)d_in[9];
    const float* Dsp    = (const float*)d_in[10];
    const float* onw    = (const float*)d_in[11];
    const float* onb    = (const float*)d_in[12];
    const float* outW   = (const float*)d_in[13];
    const float* ln2w   = (const float*)d_in[14];
    const float* ln2b   = (const float*)d_in[15];
    const float* fc1W   = (const float*)d_in[16];
    const float* fc1b   = (const float*)d_in[17];
    const float* fc2W   = (const float*)d_in[18];
    const float* fc2b   = (const float*)d_in[19];
    float* out = (float*)d_out;

    char* ws = (char*)d_ws;
    unsigned short* z_us    = (unsigned short*)(ws + 0);           // [G1..k65]
    bf16*  z_bf             = (bf16*)z_us;
    bf16*  xconv_bf         = (bf16*)(ws + 9633792);               // [k2..k6]
    float* proj_f           = (float*)(ws + 19267584);             // [G2..k6]
    bf16*  ymod_bf          = (bf16*)(ws + 19267584);              // [k65..G3]
    unsigned short* xn_us   = (unsigned short*)(ws + 34521088);    // [LN1..G1]
    float* tsum_f           = (float*)(ws + 34521088);             // [k4..k6]
    unsigned short* xcpre_us= (unsigned short*)(ws + 39337984);    // [G1..k2]
    float* hloc_f           = (float*)(ws + 48971776);             // [k4..k6]
    float* hin_f            = hloc_f;                              // k5 r-b-w alias
    float* y1_f             = (float*)(ws + 48971776);             // [G3..G5]
    unsigned short* y1n_us  = (unsigned short*)(ws + 58605568);    // [LN2..G4]
    bf16*  ysm_bf           = (bf16*)(ws + 74137600);              // [k6..k65]
    unsigned short* hmlp_us = (unsigned short*)(ws + 74137600);    // [G4..G5]

    ln_rows<<<6272, 256, 0, stream>>>(x, ln1w, ln1b, xn_us);
    gemm_mfma<384, 96, 0><<<dim3(98, 6), 256, 0, stream>>>(
        xn_us, inpW, nullptr, nullptr, xcpre_us, z_us);
    k2_conv<<<9408, 256, 0, stream>>>(xcpre_us, convW, convB,
                                      (unsigned short*)xconv_bf);
    gemm_mfma<152, 192, 1><<<dim3(98, 3), 256, 0, stream>>>(
        (const unsigned short*)xconv_bf, xprojW, nullptr, nullptr, proj_f, nullptr);
    k4_scan1<<<2048, 192, 0, stream>>>(xconv_bf, proj_f, dtW, dtB, Alog, hloc_f, tsum_f);
    k5_carry<<<384, 256, 0, stream>>>(hloc_f, tsum_f, Alog, hin_f);
    k6_scan2<<<2048, 192, 0, stream>>>(xconv_bf, proj_f, dtW, dtB, Alog, Dsp, hin_f, ysm_bf);
    k65_merge<<<1568, 256, 0, stream>>>(ysm_bf, z_bf, onw, onb, ymod_bf);
    gemm_mfma<96, 192, 2><<<dim3(98, 2), 256, 0, stream>>>(
        (const unsigned short*)ymod_bf, outW, nullptr, x, y1_f, nullptr);
    ln_rows<<<6272, 256, 0, stream>>>(y1_f, ln2w, ln2b, y1n_us);
    gemm_mfma<384, 96, 3><<<dim3(98, 6), 256, 0, stream>>>(
        y1n_us, fc1W, fc1b, nullptr, hmlp_us, nullptr);
    gemm_mfma<96, 384, 4><<<dim3(98, 2), 256, 0, stream>>>(
        hmlp_us, fc2W, fc2b, y1_f, out, nullptr);
}

// Round 6
// 388.540 us; speedup vs baseline: 1.1287x; 1.0206x over previous
//
#include <hip/hip_runtime.h>
#include <hip/hip_bf16.h>

typedef __hip_bfloat16 bf16;
typedef short bf16x8 __attribute__((ext_vector_type(8)));
typedef float f32x4 __attribute__((ext_vector_type(4)));

#define BBATCH 8
#define HHH 56
#define WWW 56
#define CCH 96          // C
#define DIN 192         // D
#define NST 16          // N
#define KDIR 4          // K
#define RDT 6           // R
#define LLEN 3136       // H*W
#define BLTOT 25088     // B*L
#define SSEG 64         // segments
#define SEGL 49         // L / SSEG
#define PJC 38          // R + 2N
#define PJW 152         // K * PJC
#define PJS 40          // padded LDS row stride (16B aligned)
#define PJS1 24         // pass-1 padded row stride (r+B only)
#define MLPH 384

// native exp2/log2 (v_exp_f32 / v_log_f32) with safe fallbacks
#if defined(__has_builtin)
#if __has_builtin(__builtin_amdgcn_exp2f)
#define EXP2F(x) __builtin_amdgcn_exp2f(x)
#endif
#if __has_builtin(__builtin_amdgcn_logf)
#define LOG2F_(x) __builtin_amdgcn_logf(x)
#endif
#endif
#ifndef EXP2F
#define EXP2F(x) __expf((x) * 0.69314718056f)
#endif
#ifndef LOG2F_
#define LOG2F_(x) (__logf(x) * 1.44269504f)
#endif
#define LOG2E 1.44269504f

__device__ __forceinline__ float b2f(bf16 v) { return __bfloat162float(v); }
__device__ __forceinline__ bf16  f2b(float v) { return __float2bfloat16(v); }
__device__ __forceinline__ unsigned short f2bu(float f) {
    union { bf16 h; unsigned short u; } c; c.h = __float2bfloat16(f); return c.u;
}
__device__ __forceinline__ float sigm(float x) { return 1.f / (1.f + __expf(-x)); }
__device__ __forceinline__ float softplusf(float x) {
    float t = EXP2F(-fabsf(x) * LOG2E);
    return fmaxf(x, 0.f) + 0.69314718f * LOG2F_(1.f + t);
}
__device__ __forceinline__ float geluf(float v) {
    float u = 0.7978845608028654f * (v + 0.044715f * v * v * v);
    float ey = __expf(2.f * u);
    float th = 1.f - 2.f / (ey + 1.f);
    return 0.5f * v * (1.f + th);
}

// scan-step l -> spatial position (row-major h*56+w) for direction k
__device__ __forceinline__ int pos_map(int k, int l) {
    if (k & 2) l = LLEN - 1 - l;
    if (k & 1) { int q = l / WWW; int r = l - q * WWW; return r * WWW + q; }
    return l;
}

// ---- LN: one wave per row of 96, emit bf16 ---------------------------------
__global__ __launch_bounds__(256) void ln_rows(
    const float* __restrict__ xin, const float* __restrict__ w,
    const float* __restrict__ b, unsigned short* __restrict__ xn) {
    int row = blockIdx.x * 4 + (threadIdx.x >> 6);
    int lane = threadIdx.x & 63;
    const float* xr = xin + (size_t)row * 96;
    float2 v = make_float2(0.f, 0.f);
    if (lane < 48) v = *(const float2*)&xr[lane * 2];
    float s = v.x + v.y, s2 = v.x * v.x + v.y * v.y;
    for (int o = 32; o; o >>= 1) {
        s += __shfl_down(s, o);
        s2 += __shfl_down(s2, o);
    }
    s = __shfl(s, 0); s2 = __shfl(s2, 0);
    float m = s * (1.f / 96.f);
    float var = s2 * (1.f / 96.f) - m * m;
    float rs = rsqrtf(var + 1e-5f);
    if (lane < 48) {
        float o0 = (v.x - m) * rs * w[lane * 2] + b[lane * 2];
        float o1 = (v.y - m) * rs * w[lane * 2 + 1] + b[lane * 2 + 1];
        ushort2 u; u.x = f2bu(o0); u.y = f2bu(o1);
        *(ushort2*)&xn[(size_t)row * 96 + lane * 2] = u;
    }
}

// ---- Unified MFMA GEMM: C[M=25088][N] = X[M][K](bf16) . W[N][K]^T(f32) -----
// block: 4 waves, each wave a 32-row M-strip, 2x4 frags -> 128M x 64N tile.
// EPI: 0=split xc/z  1=proj f32  2=+res f32  3=gelu(+bias) bf16  4=+bias+res f32
template<int N, int K, int EPI>
__global__ __launch_bounds__(256) void gemm_mfma(
    const unsigned short* __restrict__ X, const float* __restrict__ W,
    const float* __restrict__ bias, const float* __restrict__ res,
    void* __restrict__ out0v, void* __restrict__ out1v) {
    __shared__ unsigned short a_sh[128 * 40];
    __shared__ unsigned short b_sh[64 * 40];
    const int t = threadIdx.x;
    const int P0 = blockIdx.x * 128;
    const int N0 = blockIdx.y * 64;
    const int w = t >> 6, lane = t & 63, q = lane >> 4, nl = lane & 15;
    f32x4 acc[2][4];
#pragma unroll
    for (int i = 0; i < 2; ++i)
#pragma unroll
        for (int j = 0; j < 4; ++j)
            acc[i][j] = (f32x4){0.f, 0.f, 0.f, 0.f};
    for (int k0 = 0; k0 < K; k0 += 32) {
        __syncthreads();
        // stage A: 128 rows x 32 k (bf16 pass-through)
#pragma unroll
        for (int it = 0; it < 2; ++it) {
            int idx = t + it * 256;
            int pr = idx >> 2, kq = idx & 3;
            uint4 v = *(const uint4*)&X[(size_t)(P0 + pr) * K + k0 + kq * 8];
            *(uint4*)&a_sh[pr * 40 + kq * 8] = v;
        }
        // stage B: 64 rows x 32 k, f32 -> bf16
#pragma unroll
        for (int it = 0; it < 2; ++it) {
            int idx = t + it * 256;
            int nr = idx >> 3, kq = idx & 7;
            int ng = N0 + nr; if (ng > N - 1) ng = N - 1;
            float4 v = *(const float4*)&W[(size_t)ng * K + k0 + kq * 4];
            ushort4 u;
            u.x = f2bu(v.x); u.y = f2bu(v.y); u.z = f2bu(v.z); u.w = f2bu(v.w);
            *(ushort4*)&b_sh[nr * 40 + kq * 4] = u;
        }
        __syncthreads();
        bf16x8 af[2], bfr[4];
#pragma unroll
        for (int mf = 0; mf < 2; ++mf)
            af[mf] = *(const bf16x8*)&a_sh[(w * 32 + mf * 16 + nl) * 40 + q * 8];
#pragma unroll
        for (int nf = 0; nf < 4; ++nf)
            bfr[nf] = *(const bf16x8*)&b_sh[(nf * 16 + nl) * 40 + q * 8];
#pragma unroll
        for (int mf = 0; mf < 2; ++mf)
#pragma unroll
            for (int nf = 0; nf < 4; ++nf)
                acc[mf][nf] = __builtin_amdgcn_mfma_f32_16x16x32_bf16(
                    af[mf], bfr[nf], acc[mf][nf], 0, 0, 0);
    }
#pragma unroll
    for (int mf = 0; mf < 2; ++mf) {
#pragma unroll
        for (int nf = 0; nf < 4; ++nf) {
#pragma unroll
            for (int r = 0; r < 4; ++r) {
                float v = acc[mf][nf][r];
                size_t pos = (size_t)P0 + w * 32 + mf * 16 + q * 4 + r;
                int n = N0 + nf * 16 + nl;
                if constexpr (EPI == 0) {
                    unsigned short* xc = (unsigned short*)out0v;
                    unsigned short* zz = (unsigned short*)out1v;
                    if (n < 192) xc[pos * 192 + n] = f2bu(v);
                    else         zz[pos * 192 + (n - 192)] = f2bu(v);
                } else if constexpr (EPI == 1) {
                    if (n < 152) ((float*)out0v)[pos * 152 + n] = v;
                } else if constexpr (EPI == 2) {
                    if (n < 96) ((float*)out0v)[pos * 96 + n] = res[pos * 96 + n] + v;
                } else if constexpr (EPI == 3) {
                    ((unsigned short*)out0v)[pos * 384 + n] = f2bu(geluf(v + bias[n]));
                } else {
                    if (n < 96) ((float*)out0v)[pos * 96 + n] =
                        res[pos * 96 + n] + bias[n] + v;
                }
            }
        }
    }
}

// ---- K2: depthwise 3x3 conv + bias + silu, 2 channels/thread ---------------
__global__ __launch_bounds__(256) void k2_conv(
    const unsigned short* __restrict__ xcpre, const float* __restrict__ cw,
    const float* __restrict__ cb, unsigned short* __restrict__ xconv) {
    int idx = blockIdx.x * 256 + threadIdx.x;
    int dd = idx % 96;
    int P = idx / 96;
    int d0 = dd * 2;
    int b = P / LLEN, l = P - b * LLEN;
    int h = l / WWW, w = l - h * WWW;
    float acc0 = cb[d0], acc1 = cb[d0 + 1];
#pragma unroll
    for (int i = 0; i < 3; ++i) {
        int hh = h + i - 1;
        if (hh < 0 || hh >= HHH) continue;
#pragma unroll
        for (int j = 0; j < 3; ++j) {
            int ww = w + j - 1;
            if (ww < 0 || ww >= WWW) continue;
            ushort2 xv = *(const ushort2*)&xcpre[
                ((size_t)(b * LLEN + hh * WWW + ww)) * DIN + d0];
            union { unsigned short u; bf16 h_; } c0, c1;
            c0.u = xv.x; c1.u = xv.y;
            acc0 = fmaf(b2f(c0.h_), cw[d0 * 9 + i * 3 + j], acc0);
            acc1 = fmaf(b2f(c1.h_), cw[(d0 + 1) * 9 + i * 3 + j], acc1);
        }
    }
    acc0 = acc0 * sigm(acc0);
    acc1 = acc1 * sigm(acc1);
    ushort2 o; o.x = f2bu(acc0); o.y = f2bu(acc1);
    *(ushort2*)&xconv[(size_t)P * DIN + d0] = o;
}

// ---- K4: scan pass 1 — split-N: lane pair (2d,2d+1) covers 8+8 states ------
__global__ __launch_bounds__(384) void k4_scan1(
    const bf16* __restrict__ xconv, const float* __restrict__ proj,
    const float* __restrict__ dtw, const float* __restrict__ dtb,
    const float* __restrict__ Alog, float* __restrict__ hloc,
    float* __restrict__ tsum) {
    __shared__ float pl[SEGL * PJS1];
    __shared__ int posl[SEGL];
    const int bid = blockIdx.x;              // 2048 = 8b * 4k * 64s
    const int s = bid & 63, k = (bid >> 6) & 3, b = bid >> 8;
    const int t = threadIdx.x;
    const int d = t >> 1, half = t & 1;
    const int l0 = s * SEGL;
    for (int q = t; q < SEGL * 22; q += 384) {
        int st = q / 22, c = q - st * 22;
        int p = pos_map(k, l0 + st);
        int ofs = (c < 6) ? c : c + 2;
        pl[st * PJS1 + ofs] = proj[(size_t)(b * LLEN + p) * PJW + k * PJC + c];
    }
    if (t < SEGL) posl[t] = pos_map(k, l0 + t) * DIN;
    float w6[RDT];
#pragma unroll
    for (int r = 0; r < RDT; ++r) w6[r] = dtw[(k * DIN + d) * RDT + r];
    const float bias = dtb[k * DIN + d];
    float a2[8];
#pragma unroll
    for (int j = 0; j < 8; ++j)
        a2[j] = -__expf(Alog[(k * DIN + d) * NST + half * 8 + j]) * LOG2E;
    float h[8];
#pragma unroll
    for (int j = 0; j < 8; ++j) h[j] = 0.f;
    float T = 0.f;
    __syncthreads();
    const bf16* xg = xconv + (size_t)b * LLEN * DIN + d;
    for (int bt = 0; bt < 7; ++bt) {
        int off7[7]; float xv7[7];
#pragma unroll
        for (int i = 0; i < 7; ++i) off7[i] = posl[bt * 7 + i];
#pragma unroll
        for (int i = 0; i < 7; ++i) xv7[i] = b2f(xg[off7[i]]);
#pragma unroll
        for (int i = 0; i < 7; ++i) {
            const float* rowf = &pl[(bt * 7 + i) * PJS1];
            float4 g0 = *(const float4*)(rowf);
            float2 g1 = *(const float2*)(rowf + 4);
            float dtv = bias;
            dtv = fmaf(g0.x, w6[0], dtv); dtv = fmaf(g0.y, w6[1], dtv);
            dtv = fmaf(g0.z, w6[2], dtv); dtv = fmaf(g0.w, w6[3], dtv);
            dtv = fmaf(g1.x, w6[4], dtv); dtv = fmaf(g1.y, w6[5], dtv);
            dtv = softplusf(dtv);
            T += dtv;
            float u = dtv * xv7[i];
            float4 B0 = *(const float4*)(rowf + 8 + half * 8);
            float4 B1 = *(const float4*)(rowf + 12 + half * 8);
#pragma unroll
            for (int j = 0; j < 4; ++j) {
                float Bv = (j == 0) ? B0.x : (j == 1) ? B0.y : (j == 2) ? B0.z : B0.w;
                float e = EXP2F(dtv * a2[j]);
                h[j] = fmaf(h[j], e, u * Bv);
            }
#pragma unroll
            for (int j = 0; j < 4; ++j) {
                float Bv = (j == 0) ? B1.x : (j == 1) ? B1.y : (j == 2) ? B1.z : B1.w;
                float e = EXP2F(dtv * a2[4 + j]);
                h[4 + j] = fmaf(h[4 + j], e, u * Bv);
            }
        }
    }
    size_t base = ((size_t)bid * DIN + d) * NST + half * 8;
#pragma unroll
    for (int j = 0; j < 8; ++j) hloc[base + j] = h[j];
    if (half == 0) tsum[bid * DIN + d] = T;
}

// ---- K5: exact segment carries (hin aliases hloc: read-before-write) -------
__global__ __launch_bounds__(256) void k5_carry(
    const float* hloc, const float* __restrict__ tsum,
    const float* __restrict__ Alog, float* hin) {
    int g = blockIdx.x * 256 + threadIdx.x;   // over B*K*D*N
    int n = g & 15;
    int dk = g >> 4;
    int d = dk % DIN;
    int bk = dk / DIN;                        // b*4 + k
    int k = bk & 3;
    float a2 = -__expf(Alog[(k * DIN + d) * NST + n]) * LOG2E;
    float Hc = 0.f;
    for (int s = 0; s < SSEG; ++s) {
        int bid = bk * SSEG + s;
        size_t idx = ((size_t)bid * DIN + d) * NST + n;
        float hl = hloc[idx];
        float Tv = tsum[bid * DIN + d];
        hin[idx] = Hc;
        Hc = fmaf(EXP2F(a2 * Tv), Hc, hl);
    }
}

// ---- K6: scan pass 2 — split-N, combine halves via shfl_xor ----------------
__global__ __launch_bounds__(384) void k6_scan2(
    const bf16* __restrict__ xconv, const float* __restrict__ proj,
    const float* __restrict__ dtw, const float* __restrict__ dtb,
    const float* __restrict__ Alog, const float* __restrict__ Dsp,
    const float* __restrict__ hin, bf16* __restrict__ ysm) {
    __shared__ float pl[SEGL * PJS];
    __shared__ int posl[SEGL];
    const int bid = blockIdx.x;
    const int s = bid & 63, k = (bid >> 6) & 3, b = bid >> 8;
    const int t = threadIdx.x;
    const int d = t >> 1, half = t & 1;
    const int l0 = s * SEGL;
    for (int q = t; q < SEGL * PJC; q += 384) {
        int st = q / PJC, c = q - st * PJC;
        int p = pos_map(k, l0 + st);
        int ofs = (c < 6) ? c : c + 2;
        pl[st * PJS + ofs] = proj[(size_t)(b * LLEN + p) * PJW + k * PJC + c];
    }
    if (t < SEGL) posl[t] = pos_map(k, l0 + t) * DIN;
    float w6[RDT];
#pragma unroll
    for (int r = 0; r < RDT; ++r) w6[r] = dtw[(k * DIN + d) * RDT + r];
    const float bias = dtb[k * DIN + d];
    const float dsv = Dsp[k * DIN + d];
    float a2[8];
#pragma unroll
    for (int j = 0; j < 8; ++j)
        a2[j] = -__expf(Alog[(k * DIN + d) * NST + half * 8 + j]) * LOG2E;
    float h[8];
    size_t hbase = ((size_t)bid * DIN + d) * NST + half * 8;
#pragma unroll
    for (int j = 0; j < 8; ++j) h[j] = hin[hbase + j];
    __syncthreads();
    const bf16* xg = xconv + (size_t)b * LLEN * DIN + d;
    bf16* ysg = ysm + ((size_t)(b * KDIR + k) * LLEN) * DIN + d;
    for (int bt = 0; bt < 7; ++bt) {
        int off7[7]; float xv7[7];
#pragma unroll
        for (int i = 0; i < 7; ++i) off7[i] = posl[bt * 7 + i];
#pragma unroll
        for (int i = 0; i < 7; ++i) xv7[i] = b2f(xg[off7[i]]);
#pragma unroll
        for (int i = 0; i < 7; ++i) {
            const float* rowf = &pl[(bt * 7 + i) * PJS];
            float4 g0 = *(const float4*)(rowf);
            float2 g1 = *(const float2*)(rowf + 4);
            float dtv = bias;
            dtv = fmaf(g0.x, w6[0], dtv); dtv = fmaf(g0.y, w6[1], dtv);
            dtv = fmaf(g0.z, w6[2], dtv); dtv = fmaf(g0.w, w6[3], dtv);
            dtv = fmaf(g1.x, w6[4], dtv); dtv = fmaf(g1.y, w6[5], dtv);
            dtv = softplusf(dtv);
            float u = dtv * xv7[i];
            float y = 0.f;
            float4 B0 = *(const float4*)(rowf + 8 + half * 8);
            float4 B1 = *(const float4*)(rowf + 12 + half * 8);
            float4 C0 = *(const float4*)(rowf + 24 + half * 8);
            float4 C1 = *(const float4*)(rowf + 28 + half * 8);
#pragma unroll
            for (int j = 0; j < 4; ++j) {
                float Bv = (j == 0) ? B0.x : (j == 1) ? B0.y : (j == 2) ? B0.z : B0.w;
                float Cv = (j == 0) ? C0.x : (j == 1) ? C0.y : (j == 2) ? C0.z : C0.w;
                float e = EXP2F(dtv * a2[j]);
                h[j] = fmaf(h[j], e, u * Bv);
                y = fmaf(h[j], Cv, y);
            }
#pragma unroll
            for (int j = 0; j < 4; ++j) {
                float Bv = (j == 0) ? B1.x : (j == 1) ? B1.y : (j == 2) ? B1.z : B1.w;
                float Cv = (j == 0) ? C1.x : (j == 1) ? C1.y : (j == 2) ? C1.z : C1.w;
                float e = EXP2F(dtv * a2[4 + j]);
                h[4 + j] = fmaf(h[4 + j], e, u * Bv);
                y = fmaf(h[4 + j], Cv, y);
            }
            y += __shfl_xor(y, 1);
            if (half == 0) ysg[off7[i]] = f2b(fmaf(dsv, xv7[i], y));
        }
    }
}

// ---- K6.5: merge 4 planes + out_norm LN + *silu(z) -------------------------
__global__ __launch_bounds__(256) void k65_merge(
    const bf16* __restrict__ ysm, const bf16* __restrict__ z,
    const float* __restrict__ onw, const float* __restrict__ onb,
    bf16* __restrict__ ymod) {
    __shared__ float rb[16 * DIN];
    __shared__ float ps[256], pq[256];
    __shared__ float mrow[16], srow[16];
    const int t = threadIdx.x;
    const int P0 = blockIdx.x * 16;
    for (int q = t; q < 16 * DIN; q += 256) {
        int pos = q / DIN, c = q - pos * DIN;
        int P = P0 + pos;
        int b = P / LLEN, l = P - b * LLEN;
        size_t base = ((size_t)(b * KDIR) * LLEN + l) * DIN + c;
        size_t pstr = (size_t)LLEN * DIN;
        float v = b2f(ysm[base]) + b2f(ysm[base + pstr]) +
                  b2f(ysm[base + 2 * pstr]) + b2f(ysm[base + 3 * pstr]);
        rb[q] = v;
    }
    __syncthreads();
    {
        int pos = t >> 4, part = t & 15;
        float s = 0.f, s2 = 0.f;
        for (int i = 0; i < 12; ++i) {
            float v = rb[pos * DIN + part * 12 + i];
            s += v; s2 += v * v;
        }
        ps[pos * 16 + part] = s; pq[pos * 16 + part] = s2;
    }
    __syncthreads();
    if (t < 16) {
        float s = 0.f, s2 = 0.f;
        for (int i = 0; i < 16; ++i) { s += ps[t * 16 + i]; s2 += pq[t * 16 + i]; }
        float m = s * (1.f / DIN);
        float v = s2 * (1.f / DIN) - m * m;
        mrow[t] = m; srow[t] = rsqrtf(v + 1e-5f);
    }
    __syncthreads();
    for (int q = t; q < 16 * DIN; q += 256) {
        int pos = q / DIN, c = q - pos * DIN;
        int P = P0 + pos;
        float v = (rb[q] - mrow[pos]) * srow[pos] * onw[c] + onb[c];
        float zv = b2f(z[(size_t)P * DIN + c]);
        v *= zv * sigm(zv);
        ymod[(size_t)P * DIN + c] = f2b(v);
    }
}

extern "C" void kernel_launch(void* const* d_in, const int* in_sizes, int n_in,
                              void* d_out, int out_size, void* d_ws, size_t ws_size,
                              hipStream_t stream) {
    const float* x      = (const float*)d_in[0];
    const float* ln1w   = (const float*)d_in[1];
    const float* ln1b   = (const float*)d_in[2];
    const float* inpW   = (const float*)d_in[3];
    const float* convW  = (const float*)d_in[4];
    const float* convB  = (const float*)d_in[5];
    const float* xprojW = (const float*)d_in[6];
    const float* dtW    = (const float*)d_in[7];
    const float* dtB    = (const float*)d_in[8];
    const float* Alog   = (const float*)d_in[9];
    const float* Dsp    = (const float*)d_in[10];
    const float* onw    = (const float*)d_in[11];
    const float* onb    = (const float*)d_in[12];
    const float* outW   = (const float*)d_in[13];
    const float* ln2w   = (const float*)d_in[14];
    const float* ln2b   = (const float*)d_in[15];
    const float* fc1W   = (const float*)d_in[16];
    const float* fc1b   = (const float*)d_in[17];
    const float* fc2W   = (const float*)d_in[18];
    const float* fc2b   = (const float*)d_in[19];
    float* out = (float*)d_out;

    char* ws = (char*)d_ws;
    unsigned short* z_us    = (unsigned short*)(ws + 0);           // [G1..k65]
    bf16*  z_bf             = (bf16*)z_us;
    bf16*  xconv_bf         = (bf16*)(ws + 9633792);               // [k2..k6]
    float* proj_f           = (float*)(ws + 19267584);             // [G2..k6]
    bf16*  ymod_bf          = (bf16*)(ws + 19267584);              // [k65..G3]
    unsigned short* xn_us   = (unsigned short*)(ws + 34521088);    // [LN1..G1]
    float* tsum_f           = (float*)(ws + 34521088);             // [k4..k6]
    unsigned short* xcpre_us= (unsigned short*)(ws + 39337984);    // [G1..k2]
    float* hloc_f           = (float*)(ws + 48971776);             // [k4..k6]
    float* hin_f            = hloc_f;                              // k5 r-b-w alias
    float* y1_f             = (float*)(ws + 48971776);             // [G3..G5]
    unsigned short* y1n_us  = (unsigned short*)(ws + 58605568);    // [LN2..G4]
    bf16*  ysm_bf           = (bf16*)(ws + 74137600);              // [k6..k65]
    unsigned short* hmlp_us = (unsigned short*)(ws + 74137600);    // [G4..G5]

    ln_rows<<<6272, 256, 0, stream>>>(x, ln1w, ln1b, xn_us);
    gemm_mfma<384, 96, 0><<<dim3(196, 6), 256, 0, stream>>>(
        xn_us, inpW, nullptr, nullptr, xcpre_us, z_us);
    k2_conv<<<9408, 256, 0, stream>>>(xcpre_us, convW, convB,
                                      (unsigned short*)xconv_bf);
    gemm_mfma<152, 192, 1><<<dim3(196, 3), 256, 0, stream>>>(
        (const unsigned short*)xconv_bf, xprojW, nullptr, nullptr, proj_f, nullptr);
    k4_scan1<<<2048, 384, 0, stream>>>(xconv_bf, proj_f, dtW, dtB, Alog, hloc_f, tsum_f);
    k5_carry<<<384, 256, 0, stream>>>(hloc_f, tsum_f, Alog, hin_f);
    k6_scan2<<<2048, 384, 0, stream>>>(xconv_bf, proj_f, dtW, dtB, Alog, Dsp, hin_f, ysm_bf);
    k65_merge<<<1568, 256, 0, stream>>>(ysm_bf, z_bf, onw, onb, ymod_bf);
    gemm_mfma<96, 192, 2><<<dim3(196, 2), 256, 0, stream>>>(
        (const unsigned short*)ymod_bf, outW, nullptr, x, y1_f, nullptr);
    ln_rows<<<6272, 256, 0, stream>>>(y1_f, ln2w, ln2b, y1n_us);
    gemm_mfma<384, 96, 3><<<dim3(196, 6), 256, 0, stream>>>(
        y1n_us, fc1W, fc1b, nullptr, hmlp_us, nullptr);
    gemm_mfma<96, 384, 4><<<dim3(196, 2), 256, 0, stream>>>(
        hmlp_us, fc2W, fc2b, y1_f, out, nullptr);
}

// Round 7
// 387.177 us; speedup vs baseline: 1.1327x; 1.0035x over previous
//
#include <hip/hip_runtime.h>
#include <hip/hip_bf16.h>

typedef __hip_bfloat16 bf16;
typedef short bf16x8 __attribute__((ext_vector_type(8)));
typedef float f32x4 __attribute__((ext_vector_type(4)));

#define BBATCH 8
#define HHH 56
#define WWW 56
#define CCH 96          // C
#define DIN 192         // D
#define NST 16          // N
#define KDIR 4          // K
#define RDT 6           // R
#define LLEN 3136       // H*W
#define BLTOT 25088     // B*L
#define SSEG 64         // segments
#define SEGL 49         // L / SSEG
#define PJC 38          // R + 2N
#define PJW 152         // K * PJC
#define PJS 40          // padded LDS row stride (16B aligned)
#define PJS1 24         // pass-1 padded row stride (r+B only)
#define MLPH 384

// native exp2/log2 (v_exp_f32 / v_log_f32) with safe fallbacks
#if defined(__has_builtin)
#if __has_builtin(__builtin_amdgcn_exp2f)
#define EXP2F(x) __builtin_amdgcn_exp2f(x)
#endif
#if __has_builtin(__builtin_amdgcn_logf)
#define LOG2F_(x) __builtin_amdgcn_logf(x)
#endif
#endif
#ifndef EXP2F
#define EXP2F(x) __expf((x) * 0.69314718056f)
#endif
#ifndef LOG2F_
#define LOG2F_(x) (__logf(x) * 1.44269504f)
#endif
#define LOG2E 1.44269504f

// packed fp32 (VOP3P, gfx90a+/gfx950): one instruction, two fp32 lanes-pairs
__device__ __forceinline__ float2 pk_mul(float2 a, float2 b) {
    float2 d;
    asm("v_pk_mul_f32 %0, %1, %2" : "=v"(d) : "v"(a), "v"(b));
    return d;
}
__device__ __forceinline__ float2 pk_fma(float2 a, float2 b, float2 c) {
    float2 d;
    asm("v_pk_fma_f32 %0, %1, %2, %3" : "=v"(d) : "v"(a), "v"(b), "v"(c));
    return d;
}

__device__ __forceinline__ float b2f(bf16 v) { return __bfloat162float(v); }
__device__ __forceinline__ bf16  f2b(float v) { return __float2bfloat16(v); }
__device__ __forceinline__ unsigned short f2bu(float f) {
    union { bf16 h; unsigned short u; } c; c.h = __float2bfloat16(f); return c.u;
}
__device__ __forceinline__ float bu2f(unsigned short u) {
    union { unsigned short u; bf16 h; } c; c.u = u; return __bfloat162float(c.h);
}
__device__ __forceinline__ float sigm(float x) { return 1.f / (1.f + __expf(-x)); }
__device__ __forceinline__ float softplusf(float x) {
    float t = EXP2F(-fabsf(x) * LOG2E);
    return fmaxf(x, 0.f) + 0.69314718f * LOG2F_(1.f + t);
}
__device__ __forceinline__ float geluf(float v) {
    float u = 0.7978845608028654f * (v + 0.044715f * v * v * v);
    float ey = __expf(2.f * u);
    float th = 1.f - 2.f / (ey + 1.f);
    return 0.5f * v * (1.f + th);
}

// scan-step l -> spatial position (row-major h*56+w) for direction k
__device__ __forceinline__ int pos_map(int k, int l) {
    if (k & 2) l = LLEN - 1 - l;
    if (k & 1) { int q = l / WWW; int r = l - q * WWW; return r * WWW + q; }
    return l;
}

// ---- LN: one wave per row of 96, emit bf16 ---------------------------------
__global__ __launch_bounds__(256) void ln_rows(
    const float* __restrict__ xin, const float* __restrict__ w,
    const float* __restrict__ b, unsigned short* __restrict__ xn) {
    int row = blockIdx.x * 4 + (threadIdx.x >> 6);
    int lane = threadIdx.x & 63;
    const float* xr = xin + (size_t)row * 96;
    float2 v = make_float2(0.f, 0.f);
    if (lane < 48) v = *(const float2*)&xr[lane * 2];
    float s = v.x + v.y, s2 = v.x * v.x + v.y * v.y;
    for (int o = 32; o; o >>= 1) {
        s += __shfl_down(s, o);
        s2 += __shfl_down(s2, o);
    }
    s = __shfl(s, 0); s2 = __shfl(s2, 0);
    float m = s * (1.f / 96.f);
    float var = s2 * (1.f / 96.f) - m * m;
    float rs = rsqrtf(var + 1e-5f);
    if (lane < 48) {
        float o0 = (v.x - m) * rs * w[lane * 2] + b[lane * 2];
        float o1 = (v.y - m) * rs * w[lane * 2 + 1] + b[lane * 2 + 1];
        ushort2 u; u.x = f2bu(o0); u.y = f2bu(o1);
        *(ushort2*)&xn[(size_t)row * 96 + lane * 2] = u;
    }
}

// ---- Unified MFMA GEMM: C[M=25088][N] = X[M][K](bf16) . W[N][K]^T(f32) -----
// block: 4 waves, each wave a 32-row M-strip, 2x4 frags -> 128M x 64N tile.
// EPI: 0=split xc/z  1=proj f32  2=+res f32  3=gelu(+bias) bf16  4=+bias+res f32
template<int N, int K, int EPI>
__global__ __launch_bounds__(256) void gemm_mfma(
    const unsigned short* __restrict__ X, const float* __restrict__ W,
    const float* __restrict__ bias, const float* __restrict__ res,
    void* __restrict__ out0v, void* __restrict__ out1v) {
    __shared__ unsigned short a_sh[128 * 40];
    __shared__ unsigned short b_sh[64 * 40];
    const int t = threadIdx.x;
    const int P0 = blockIdx.x * 128;
    const int N0 = blockIdx.y * 64;
    const int w = t >> 6, lane = t & 63, q = lane >> 4, nl = lane & 15;
    f32x4 acc[2][4];
#pragma unroll
    for (int i = 0; i < 2; ++i)
#pragma unroll
        for (int j = 0; j < 4; ++j)
            acc[i][j] = (f32x4){0.f, 0.f, 0.f, 0.f};
    for (int k0 = 0; k0 < K; k0 += 32) {
        __syncthreads();
#pragma unroll
        for (int it = 0; it < 2; ++it) {
            int idx = t + it * 256;
            int pr = idx >> 2, kq = idx & 3;
            uint4 v = *(const uint4*)&X[(size_t)(P0 + pr) * K + k0 + kq * 8];
            *(uint4*)&a_sh[pr * 40 + kq * 8] = v;
        }
#pragma unroll
        for (int it = 0; it < 2; ++it) {
            int idx = t + it * 256;
            int nr = idx >> 3, kq = idx & 7;
            int ng = N0 + nr; if (ng > N - 1) ng = N - 1;
            float4 v = *(const float4*)&W[(size_t)ng * K + k0 + kq * 4];
            ushort4 u;
            u.x = f2bu(v.x); u.y = f2bu(v.y); u.z = f2bu(v.z); u.w = f2bu(v.w);
            *(ushort4*)&b_sh[nr * 40 + kq * 4] = u;
        }
        __syncthreads();
        bf16x8 af[2], bfr[4];
#pragma unroll
        for (int mf = 0; mf < 2; ++mf)
            af[mf] = *(const bf16x8*)&a_sh[(w * 32 + mf * 16 + nl) * 40 + q * 8];
#pragma unroll
        for (int nf = 0; nf < 4; ++nf)
            bfr[nf] = *(const bf16x8*)&b_sh[(nf * 16 + nl) * 40 + q * 8];
#pragma unroll
        for (int mf = 0; mf < 2; ++mf)
#pragma unroll
            for (int nf = 0; nf < 4; ++nf)
                acc[mf][nf] = __builtin_amdgcn_mfma_f32_16x16x32_bf16(
                    af[mf], bfr[nf], acc[mf][nf], 0, 0, 0);
    }
#pragma unroll
    for (int mf = 0; mf < 2; ++mf) {
#pragma unroll
        for (int nf = 0; nf < 4; ++nf) {
#pragma unroll
            for (int r = 0; r < 4; ++r) {
                float v = acc[mf][nf][r];
                size_t pos = (size_t)P0 + w * 32 + mf * 16 + q * 4 + r;
                int n = N0 + nf * 16 + nl;
                if constexpr (EPI == 0) {
                    unsigned short* xc = (unsigned short*)out0v;
                    unsigned short* zz = (unsigned short*)out1v;
                    if (n < 192) xc[pos * 192 + n] = f2bu(v);
                    else         zz[pos * 192 + (n - 192)] = f2bu(v);
                } else if constexpr (EPI == 1) {
                    if (n < 152) ((float*)out0v)[pos * 152 + n] = v;
                } else if constexpr (EPI == 2) {
                    if (n < 96) ((float*)out0v)[pos * 96 + n] = res[pos * 96 + n] + v;
                } else if constexpr (EPI == 3) {
                    ((unsigned short*)out0v)[pos * 384 + n] = f2bu(geluf(v + bias[n]));
                } else {
                    if (n < 96) ((float*)out0v)[pos * 96 + n] =
                        res[pos * 96 + n] + bias[n] + v;
                }
            }
        }
    }
}

// ---- K2: depthwise 3x3 conv + bias + silu, 4 channels/thread ---------------
__global__ __launch_bounds__(256) void k2_conv(
    const unsigned short* __restrict__ xcpre, const float* __restrict__ cw,
    const float* __restrict__ cb, unsigned short* __restrict__ xconv) {
    int idx = blockIdx.x * 256 + threadIdx.x;
    int dd = idx % 48;
    int P = idx / 48;
    int d0 = dd * 4;
    int b = P / LLEN, l = P - b * LLEN;
    int h = l / WWW, w = l - h * WWW;
    float acc0 = cb[d0], acc1 = cb[d0 + 1], acc2 = cb[d0 + 2], acc3 = cb[d0 + 3];
#pragma unroll
    for (int i = 0; i < 3; ++i) {
        int hh = h + i - 1;
        if (hh < 0 || hh >= HHH) continue;
#pragma unroll
        for (int j = 0; j < 3; ++j) {
            int ww = w + j - 1;
            if (ww < 0 || ww >= WWW) continue;
            ushort4 xv = *(const ushort4*)&xcpre[
                ((size_t)(b * LLEN + hh * WWW + ww)) * DIN + d0];
            acc0 = fmaf(bu2f(xv.x), cw[(d0 + 0) * 9 + i * 3 + j], acc0);
            acc1 = fmaf(bu2f(xv.y), cw[(d0 + 1) * 9 + i * 3 + j], acc1);
            acc2 = fmaf(bu2f(xv.z), cw[(d0 + 2) * 9 + i * 3 + j], acc2);
            acc3 = fmaf(bu2f(xv.w), cw[(d0 + 3) * 9 + i * 3 + j], acc3);
        }
    }
    acc0 = acc0 * sigm(acc0); acc1 = acc1 * sigm(acc1);
    acc2 = acc2 * sigm(acc2); acc3 = acc3 * sigm(acc3);
    ushort4 o;
    o.x = f2bu(acc0); o.y = f2bu(acc1); o.z = f2bu(acc2); o.w = f2bu(acc3);
    *(ushort4*)&xconv[(size_t)P * DIN + d0] = o;
}

// ---- K4: scan pass 1 — one segment per block, packed-fp32 inner loop -------
__global__ __launch_bounds__(192) void k4_scan1(
    const bf16* __restrict__ xconv, const float* __restrict__ proj,
    const float* __restrict__ dtw, const float* __restrict__ dtb,
    const float* __restrict__ Alog, float* __restrict__ hloc,
    float* __restrict__ tsum) {
    __shared__ float pl[SEGL * PJS1];
    __shared__ int posl[SEGL];
    const int bid = blockIdx.x;              // 2048 = 8b * 4k * 64s
    const int s = bid & 63, k = (bid >> 6) & 3, b = bid >> 8;
    const int d = threadIdx.x;
    const int l0 = s * SEGL;
    for (int q = d; q < SEGL * 22; q += 192) {
        int st = q / 22, c = q - st * 22;
        int p = pos_map(k, l0 + st);
        int ofs = (c < 6) ? c : c + 2;
        pl[st * PJS1 + ofs] = proj[(size_t)(b * LLEN + p) * PJW + k * PJC + c];
    }
    if (d < SEGL) posl[d] = pos_map(k, l0 + d) * DIN;
    float w6[RDT];
#pragma unroll
    for (int r = 0; r < RDT; ++r) w6[r] = dtw[(k * DIN + d) * RDT + r];
    const float bias = dtb[k * DIN + d];
    float2 a2[8];
#pragma unroll
    for (int j = 0; j < 8; ++j) {
        a2[j].x = -__expf(Alog[(k * DIN + d) * NST + 2 * j]) * LOG2E;
        a2[j].y = -__expf(Alog[(k * DIN + d) * NST + 2 * j + 1]) * LOG2E;
    }
    float2 h2[8];
#pragma unroll
    for (int j = 0; j < 8; ++j) h2[j] = make_float2(0.f, 0.f);
    float T = 0.f;
    __syncthreads();
    const bf16* xg = xconv + (size_t)b * LLEN * DIN + d;
    for (int bt = 0; bt < 7; ++bt) {
        int off7[7]; float xv7[7];
#pragma unroll
        for (int i = 0; i < 7; ++i) off7[i] = posl[bt * 7 + i];
#pragma unroll
        for (int i = 0; i < 7; ++i) xv7[i] = b2f(xg[off7[i]]);
#pragma unroll
        for (int i = 0; i < 7; ++i) {
            const float* rowf = &pl[(bt * 7 + i) * PJS1];
            float4 g0 = *(const float4*)(rowf);
            float2 g1 = *(const float2*)(rowf + 4);
            float dtv = bias;
            dtv = fmaf(g0.x, w6[0], dtv); dtv = fmaf(g0.y, w6[1], dtv);
            dtv = fmaf(g0.z, w6[2], dtv); dtv = fmaf(g0.w, w6[3], dtv);
            dtv = fmaf(g1.x, w6[4], dtv); dtv = fmaf(g1.y, w6[5], dtv);
            dtv = softplusf(dtv);
            T += dtv;
            float2 dt2 = make_float2(dtv, dtv);
            float2 u2 = make_float2(dtv * xv7[i], dtv * xv7[i]);
#pragma unroll
            for (int g = 0; g < 4; ++g) {
                float4 Bv = *(const float4*)(rowf + 8 + 4 * g);
                float2 Blo = make_float2(Bv.x, Bv.y);
                float2 Bhi = make_float2(Bv.z, Bv.w);
                float2 alo = pk_mul(dt2, a2[2 * g]);
                float2 ahi = pk_mul(dt2, a2[2 * g + 1]);
                float2 elo, ehi;
                elo.x = EXP2F(alo.x); elo.y = EXP2F(alo.y);
                ehi.x = EXP2F(ahi.x); ehi.y = EXP2F(ahi.y);
                h2[2 * g]     = pk_fma(h2[2 * g],     elo, pk_mul(u2, Blo));
                h2[2 * g + 1] = pk_fma(h2[2 * g + 1], ehi, pk_mul(u2, Bhi));
            }
        }
    }
    size_t base = ((size_t)bid * DIN + d) * NST;
#pragma unroll
    for (int j = 0; j < 8; ++j) *(float2*)&hloc[base + 2 * j] = h2[j];
    tsum[bid * DIN + d] = T;
}

// ---- K5: exact segment carries (hin aliases hloc: read-before-write) -------
__global__ __launch_bounds__(256) void k5_carry(
    const float* hloc, const float* __restrict__ tsum,
    const float* __restrict__ Alog, float* hin) {
    int g = blockIdx.x * 256 + threadIdx.x;   // over B*K*D*N
    int n = g & 15;
    int dk = g >> 4;
    int d = dk % DIN;
    int bk = dk / DIN;                        // b*4 + k
    int k = bk & 3;
    float a2 = -__expf(Alog[(k * DIN + d) * NST + n]) * LOG2E;
    float Hc = 0.f;
    for (int s = 0; s < SSEG; ++s) {
        int bid = bk * SSEG + s;
        size_t idx = ((size_t)bid * DIN + d) * NST + n;
        float hl = hloc[idx];
        float Tv = tsum[bid * DIN + d];
        hin[idx] = Hc;
        Hc = fmaf(EXP2F(a2 * Tv), Hc, hl);
    }
}

// ---- K6: scan pass 2 — one segment per block, packed-fp32, split y-chains --
__global__ __launch_bounds__(192) void k6_scan2(
    const bf16* __restrict__ xconv, const float* __restrict__ proj,
    const float* __restrict__ dtw, const float* __restrict__ dtb,
    const float* __restrict__ Alog, const float* __restrict__ Dsp,
    const float* __restrict__ hin, bf16* __restrict__ ysm) {
    __shared__ float pl[SEGL * PJS];
    __shared__ int posl[SEGL];
    const int bid = blockIdx.x;
    const int s = bid & 63, k = (bid >> 6) & 3, b = bid >> 8;
    const int d = threadIdx.x;
    const int l0 = s * SEGL;
    for (int q = d; q < SEGL * PJC; q += 192) {
        int st = q / PJC, c = q - st * PJC;
        int p = pos_map(k, l0 + st);
        int ofs = (c < 6) ? c : c + 2;
        pl[st * PJS + ofs] = proj[(size_t)(b * LLEN + p) * PJW + k * PJC + c];
    }
    if (d < SEGL) posl[d] = pos_map(k, l0 + d) * DIN;
    float w6[RDT];
#pragma unroll
    for (int r = 0; r < RDT; ++r) w6[r] = dtw[(k * DIN + d) * RDT + r];
    const float bias = dtb[k * DIN + d];
    const float dsv = Dsp[k * DIN + d];
    float2 a2[8];
#pragma unroll
    for (int j = 0; j < 8; ++j) {
        a2[j].x = -__expf(Alog[(k * DIN + d) * NST + 2 * j]) * LOG2E;
        a2[j].y = -__expf(Alog[(k * DIN + d) * NST + 2 * j + 1]) * LOG2E;
    }
    float2 h2[8];
    size_t hbase = ((size_t)bid * DIN + d) * NST;
#pragma unroll
    for (int j = 0; j < 8; ++j) h2[j] = *(const float2*)&hin[hbase + 2 * j];
    __syncthreads();
    const bf16* xg = xconv + (size_t)b * LLEN * DIN + d;
    bf16* ysg = ysm + ((size_t)(b * KDIR + k) * LLEN) * DIN + d;
    for (int bt = 0; bt < 7; ++bt) {
        int off7[7]; float xv7[7];
#pragma unroll
        for (int i = 0; i < 7; ++i) off7[i] = posl[bt * 7 + i];
#pragma unroll
        for (int i = 0; i < 7; ++i) xv7[i] = b2f(xg[off7[i]]);
#pragma unroll
        for (int i = 0; i < 7; ++i) {
            const float* rowf = &pl[(bt * 7 + i) * PJS];
            float4 g0 = *(const float4*)(rowf);
            float2 g1 = *(const float2*)(rowf + 4);
            float dtv = bias;
            dtv = fmaf(g0.x, w6[0], dtv); dtv = fmaf(g0.y, w6[1], dtv);
            dtv = fmaf(g0.z, w6[2], dtv); dtv = fmaf(g0.w, w6[3], dtv);
            dtv = fmaf(g1.x, w6[4], dtv); dtv = fmaf(g1.y, w6[5], dtv);
            dtv = softplusf(dtv);
            float2 dt2 = make_float2(dtv, dtv);
            float2 u2 = make_float2(dtv * xv7[i], dtv * xv7[i]);
            float2 yac0 = make_float2(0.f, 0.f), yac1 = make_float2(0.f, 0.f);
#pragma unroll
            for (int g = 0; g < 4; ++g) {
                float4 Bv = *(const float4*)(rowf + 8 + 4 * g);
                float4 Cv = *(const float4*)(rowf + 24 + 4 * g);
                float2 Blo = make_float2(Bv.x, Bv.y);
                float2 Bhi = make_float2(Bv.z, Bv.w);
                float2 Clo = make_float2(Cv.x, Cv.y);
                float2 Chi = make_float2(Cv.z, Cv.w);
                float2 alo = pk_mul(dt2, a2[2 * g]);
                float2 ahi = pk_mul(dt2, a2[2 * g + 1]);
                float2 elo, ehi;
                elo.x = EXP2F(alo.x); elo.y = EXP2F(alo.y);
                ehi.x = EXP2F(ahi.x); ehi.y = EXP2F(ahi.y);
                h2[2 * g]     = pk_fma(h2[2 * g],     elo, pk_mul(u2, Blo));
                h2[2 * g + 1] = pk_fma(h2[2 * g + 1], ehi, pk_mul(u2, Bhi));
                yac0 = pk_fma(h2[2 * g],     Clo, yac0);
                yac1 = pk_fma(h2[2 * g + 1], Chi, yac1);
            }
            float y = (yac0.x + yac0.y) + (yac1.x + yac1.y);
            ysg[off7[i]] = f2b(fmaf(dsv, xv7[i], y));
        }
    }
}

// ---- K6.5: merge 4 planes + out_norm LN + *silu(z) -------------------------
__global__ __launch_bounds__(256) void k65_merge(
    const bf16* __restrict__ ysm, const bf16* __restrict__ z,
    const float* __restrict__ onw, const float* __restrict__ onb,
    bf16* __restrict__ ymod) {
    __shared__ float rb[16 * DIN];
    __shared__ float ps[256], pq[256];
    __shared__ float mrow[16], srow[16];
    const int t = threadIdx.x;
    const int P0 = blockIdx.x * 16;
    for (int q = t; q < 16 * DIN; q += 256) {
        int pos = q / DIN, c = q - pos * DIN;
        int P = P0 + pos;
        int b = P / LLEN, l = P - b * LLEN;
        size_t base = ((size_t)(b * KDIR) * LLEN + l) * DIN + c;
        size_t pstr = (size_t)LLEN * DIN;
        float v = b2f(ysm[base]) + b2f(ysm[base + pstr]) +
                  b2f(ysm[base + 2 * pstr]) + b2f(ysm[base + 3 * pstr]);
        rb[q] = v;
    }
    __syncthreads();
    {
        int pos = t >> 4, part = t & 15;
        float s = 0.f, s2 = 0.f;
        for (int i = 0; i < 12; ++i) {
            float v = rb[pos * DIN + part * 12 + i];
            s += v; s2 += v * v;
        }
        ps[pos * 16 + part] = s; pq[pos * 16 + part] = s2;
    }
    __syncthreads();
    if (t < 16) {
        float s = 0.f, s2 = 0.f;
        for (int i = 0; i < 16; ++i) { s += ps[t * 16 + i]; s2 += pq[t * 16 + i]; }
        float m = s * (1.f / DIN);
        float v = s2 * (1.f / DIN) - m * m;
        mrow[t] = m; srow[t] = rsqrtf(v + 1e-5f);
    }
    __syncthreads();
    for (int q = t; q < 16 * DIN; q += 256) {
        int pos = q / DIN, c = q - pos * DIN;
        int P = P0 + pos;
        float v = (rb[q] - mrow[pos]) * srow[pos] * onw[c] + onb[c];
        float zv = b2f(z[(size_t)P * DIN + c]);
        v *= zv * sigm(zv);
        ymod[(size_t)P * DIN + c] = f2b(v);
    }
}

extern "C" void kernel_launch(void* const* d_in, const int* in_sizes, int n_in,
                              void* d_out, int out_size, void* d_ws, size_t ws_size,
                              hipStream_t stream) {
    const float* x      = (const float*)d_in[0];
    const float* ln1w   = (const float*)d_in[1];
    const float* ln1b   = (const float*)d_in[2];
    const float* inpW   = (const float*)d_in[3];
    const float* convW  = (const float*)d_in[4];
    const float* convB  = (const float*)d_in[5];
    const float* xprojW = (const float*)d_in[6];
    const float* dtW    = (const float*)d_in[7];
    const float* dtB    = (const float*)d_in[8];
    const float* Alog   = (const float*)d_in[9];
    const float* Dsp    = (const float*)d_in[10];
    const float* onw    = (const float*)d_in[11];
    const float* onb    = (const float*)d_in[12];
    const float* outW   = (const float*)d_in[13];
    const float* ln2w   = (const float*)d_in[14];
    const float* ln2b   = (const float*)d_in[15];
    const float* fc1W   = (const float*)d_in[16];
    const float* fc1b   = (const float*)d_in[17];
    const float* fc2W   = (const float*)d_in[18];
    const float* fc2b   = (const float*)d_in[19];
    float* out = (float*)d_out;

    char* ws = (char*)d_ws;
    unsigned short* z_us    = (unsigned short*)(ws + 0);           // [G1..k65]
    bf16*  z_bf             = (bf16*)z_us;
    bf16*  xconv_bf         = (bf16*)(ws + 9633792);               // [k2..k6]
    float* proj_f           = (float*)(ws + 19267584);             // [G2..k6]
    bf16*  ymod_bf          = (bf16*)(ws + 19267584);              // [k65..G3]
    unsigned short* xn_us   = (unsigned short*)(ws + 34521088);    // [LN1..G1]
    float* tsum_f           = (float*)(ws + 34521088);             // [k4..k6]
    unsigned short* xcpre_us= (unsigned short*)(ws + 39337984);    // [G1..k2]
    float* hloc_f           = (float*)(ws + 48971776);             // [k4..k6]
    float* hin_f            = hloc_f;                              // k5 r-b-w alias
    float* y1_f             = (float*)(ws + 48971776);             // [G3..G5]
    unsigned short* y1n_us  = (unsigned short*)(ws + 58605568);    // [LN2..G4]
    bf16*  ysm_bf           = (bf16*)(ws + 74137600);              // [k6..k65]
    unsigned short* hmlp_us = (unsigned short*)(ws + 74137600);    // [G4..G5]

    ln_rows<<<6272, 256, 0, stream>>>(x, ln1w, ln1b, xn_us);
    gemm_mfma<384, 96, 0><<<dim3(196, 6), 256, 0, stream>>>(
        xn_us, inpW, nullptr, nullptr, xcpre_us, z_us);
    k2_conv<<<4704, 256, 0, stream>>>(xcpre_us, convW, convB,
                                      (unsigned short*)xconv_bf);
    gemm_mfma<152, 192, 1><<<dim3(196, 3), 256, 0, stream>>>(
        (const unsigned short*)xconv_bf, xprojW, nullptr, nullptr, proj_f, nullptr);
    k4_scan1<<<2048, 192, 0, stream>>>(xconv_bf, proj_f, dtW, dtB, Alog, hloc_f, tsum_f);
    k5_carry<<<384, 256, 0, stream>>>(hloc_f, tsum_f, Alog, hin_f);
    k6_scan2<<<2048, 192, 0, stream>>>(xconv_bf, proj_f, dtW, dtB, Alog, Dsp, hin_f, ysm_bf);
    k65_merge<<<1568, 256, 0, stream>>>(ysm_bf, z_bf, onw, onb, ymod_bf);
    gemm_mfma<96, 192, 2><<<dim3(196, 2), 256, 0, stream>>>(
        (const unsigned short*)ymod_bf, outW, nullptr, x, y1_f, nullptr);
    ln_rows<<<6272, 256, 0, stream>>>(y1_f, ln2w, ln2b, y1n_us);
    gemm_mfma<384, 96, 3><<<dim3(196, 6), 256, 0, stream>>>(
        y1n_us, fc1W, fc1b, nullptr, hmlp_us, nullptr);
    gemm_mfma<96, 384, 4><<<dim3(196, 2), 256, 0, stream>>>(
        hmlp_us, fc2W, fc2b, y1_f, out, nullptr);
}

// Round 9
// 379.514 us; speedup vs baseline: 1.1555x; 1.0202x over previous
//
#include <hip/hip_runtime.h>
#include <hip/hip_bf16.h>

typedef __hip_bfloat16 bf16;
typedef short bf16x8 __attribute__((ext_vector_type(8)));
typedef float f32x4 __attribute__((ext_vector_type(4)));

#define BBATCH 8
#define HHH 56
#define WWW 56
#define CCH 96          // C
#define DIN 192         // D
#define NST 16          // N
#define KDIR 4          // K
#define RDT 6           // R
#define LLEN 3136       // H*W
#define BLTOT 25088     // B*L
#define SSEG 112        // segments (112 * 28 = 3136)
#define SEGL 28         // L / SSEG
#define PJC 38          // R + 2N
#define PJW 152         // K * PJC
#define PJS 40          // padded LDS row stride (16B aligned)
#define PJS1 24         // pass-1 padded row stride (r+B only)
#define MLPH 384

// native exp2/log2 (v_exp_f32 / v_log_f32) with safe fallbacks
#if defined(__has_builtin)
#if __has_builtin(__builtin_amdgcn_exp2f)
#define EXP2F(x) __builtin_amdgcn_exp2f(x)
#endif
#if __has_builtin(__builtin_amdgcn_logf)
#define LOG2F_(x) __builtin_amdgcn_logf(x)
#endif
#endif
#ifndef EXP2F
#define EXP2F(x) __expf((x) * 0.69314718056f)
#endif
#ifndef LOG2F_
#define LOG2F_(x) (__logf(x) * 1.44269504f)
#endif
#define LOG2E 1.44269504f

// packed fp32 (VOP3P, gfx90a+/gfx950)
__device__ __forceinline__ float2 pk_mul(float2 a, float2 b) {
    float2 d;
    asm("v_pk_mul_f32 %0, %1, %2" : "=v"(d) : "v"(a), "v"(b));
    return d;
}
__device__ __forceinline__ float2 pk_fma(float2 a, float2 b, float2 c) {
    float2 d;
    asm("v_pk_fma_f32 %0, %1, %2, %3" : "=v"(d) : "v"(a), "v"(b), "v"(c));
    return d;
}

__device__ __forceinline__ float b2f(bf16 v) { return __bfloat162float(v); }
__device__ __forceinline__ bf16  f2b(float v) { return __float2bfloat16(v); }
__device__ __forceinline__ unsigned short f2bu(float f) {
    union { bf16 h; unsigned short u; } c; c.h = __float2bfloat16(f); return c.u;
}
__device__ __forceinline__ float bu2f(unsigned short u) {
    union { unsigned short u; bf16 h; } c; c.u = u; return __bfloat162float(c.h);
}
__device__ __forceinline__ float sigm(float x) { return 1.f / (1.f + __expf(-x)); }
__device__ __forceinline__ float softplusf(float x) {
    float t = EXP2F(-fabsf(x) * LOG2E);
    return fmaxf(x, 0.f) + 0.69314718f * LOG2F_(1.f + t);
}
__device__ __forceinline__ float geluf(float v) {
    float u = 0.7978845608028654f * (v + 0.044715f * v * v * v);
    float ey = __expf(2.f * u);
    float th = 1.f - 2.f / (ey + 1.f);
    return 0.5f * v * (1.f + th);
}

// scan-step l -> spatial position (row-major h*56+w) for direction k
__device__ __forceinline__ int pos_map(int k, int l) {
    if (k & 2) l = LLEN - 1 - l;
    if (k & 1) { int q = l / WWW; int r = l - q * WWW; return r * WWW + q; }
    return l;
}

// ---- K0: precompute a2[k][d][n] = -exp(Alog)*log2e --------------------------
__global__ __launch_bounds__(256) void k0_pre(
    const float* __restrict__ Alog, float* __restrict__ a2g) {
    int i = blockIdx.x * 256 + threadIdx.x;   // over K*D*N = 12288
    a2g[i] = -__expf(Alog[i]) * LOG2E;
}

// ---- LN: one wave per row of 96, emit bf16 ---------------------------------
__global__ __launch_bounds__(256) void ln_rows(
    const float* __restrict__ xin, const float* __restrict__ w,
    const float* __restrict__ b, unsigned short* __restrict__ xn) {
    int row = blockIdx.x * 4 + (threadIdx.x >> 6);
    int lane = threadIdx.x & 63;
    const float* xr = xin + (size_t)row * 96;
    float2 v = make_float2(0.f, 0.f);
    if (lane < 48) v = *(const float2*)&xr[lane * 2];
    float s = v.x + v.y, s2 = v.x * v.x + v.y * v.y;
    for (int o = 32; o; o >>= 1) {
        s += __shfl_down(s, o);
        s2 += __shfl_down(s2, o);
    }
    s = __shfl(s, 0); s2 = __shfl(s2, 0);
    float m = s * (1.f / 96.f);
    float var = s2 * (1.f / 96.f) - m * m;
    float rs = rsqrtf(var + 1e-5f);
    if (lane < 48) {
        float o0 = (v.x - m) * rs * w[lane * 2] + b[lane * 2];
        float o1 = (v.y - m) * rs * w[lane * 2 + 1] + b[lane * 2 + 1];
        ushort2 u; u.x = f2bu(o0); u.y = f2bu(o1);
        *(ushort2*)&xn[(size_t)row * 96 + lane * 2] = u;
    }
}

// ---- Unified MFMA GEMM: C[M=25088][N] = X[M][K](bf16) . W[N][K]^T(f32) -----
// block: 4 waves, each wave a 32-row M-strip, 2x4 frags -> 128M x 64N tile.
// EPI: 0=split xc/z  1=proj f32  2=+res f32  3=gelu(+bias) bf16  4=+bias+res f32
template<int N, int K, int EPI>
__global__ __launch_bounds__(256) void gemm_mfma(
    const unsigned short* __restrict__ X, const float* __restrict__ W,
    const float* __restrict__ bias, const float* __restrict__ res,
    void* __restrict__ out0v, void* __restrict__ out1v) {
    __shared__ unsigned short a_sh[128 * 40];
    __shared__ unsigned short b_sh[64 * 40];
    const int t = threadIdx.x;
    const int P0 = blockIdx.x * 128;
    const int N0 = blockIdx.y * 64;
    const int w = t >> 6, lane = t & 63, q = lane >> 4, nl = lane & 15;
    f32x4 acc[2][4];
#pragma unroll
    for (int i = 0; i < 2; ++i)
#pragma unroll
        for (int j = 0; j < 4; ++j)
            acc[i][j] = (f32x4){0.f, 0.f, 0.f, 0.f};
    for (int k0 = 0; k0 < K; k0 += 32) {
        __syncthreads();
#pragma unroll
        for (int it = 0; it < 2; ++it) {
            int idx = t + it * 256;
            int pr = idx >> 2, kq = idx & 3;
            uint4 v = *(const uint4*)&X[(size_t)(P0 + pr) * K + k0 + kq * 8];
            *(uint4*)&a_sh[pr * 40 + kq * 8] = v;
        }
#pragma unroll
        for (int it = 0; it < 2; ++it) {
            int idx = t + it * 256;
            int nr = idx >> 3, kq = idx & 7;
            int ng = N0 + nr; if (ng > N - 1) ng = N - 1;
            float4 v = *(const float4*)&W[(size_t)ng * K + k0 + kq * 4];
            ushort4 u;
            u.x = f2bu(v.x); u.y = f2bu(v.y); u.z = f2bu(v.z); u.w = f2bu(v.w);
            *(ushort4*)&b_sh[nr * 40 + kq * 4] = u;
        }
        __syncthreads();
        bf16x8 af[2], bfr[4];
#pragma unroll
        for (int mf = 0; mf < 2; ++mf)
            af[mf] = *(const bf16x8*)&a_sh[(w * 32 + mf * 16 + nl) * 40 + q * 8];
#pragma unroll
        for (int nf = 0; nf < 4; ++nf)
            bfr[nf] = *(const bf16x8*)&b_sh[(nf * 16 + nl) * 40 + q * 8];
#pragma unroll
        for (int mf = 0; mf < 2; ++mf)
#pragma unroll
            for (int nf = 0; nf < 4; ++nf)
                acc[mf][nf] = __builtin_amdgcn_mfma_f32_16x16x32_bf16(
                    af[mf], bfr[nf], acc[mf][nf], 0, 0, 0);
    }
#pragma unroll
    for (int mf = 0; mf < 2; ++mf) {
#pragma unroll
        for (int nf = 0; nf < 4; ++nf) {
#pragma unroll
            for (int r = 0; r < 4; ++r) {
                float v = acc[mf][nf][r];
                size_t pos = (size_t)P0 + w * 32 + mf * 16 + q * 4 + r;
                int n = N0 + nf * 16 + nl;
                if constexpr (EPI == 0) {
                    unsigned short* xc = (unsigned short*)out0v;
                    unsigned short* zz = (unsigned short*)out1v;
                    if (n < 192) xc[pos * 192 + n] = f2bu(v);
                    else         zz[pos * 192 + (n - 192)] = f2bu(v);
                } else if constexpr (EPI == 1) {
                    if (n < 152) ((float*)out0v)[pos * 152 + n] = v;
                } else if constexpr (EPI == 2) {
                    if (n < 96) ((float*)out0v)[pos * 96 + n] = res[pos * 96 + n] + v;
                } else if constexpr (EPI == 3) {
                    ((unsigned short*)out0v)[pos * 384 + n] = f2bu(geluf(v + bias[n]));
                } else {
                    if (n < 96) ((float*)out0v)[pos * 96 + n] =
                        res[pos * 96 + n] + bias[n] + v;
                }
            }
        }
    }
}

// ---- K2: depthwise 3x3 conv + bias + silu, 4 channels/thread ---------------
__global__ __launch_bounds__(256) void k2_conv(
    const unsigned short* __restrict__ xcpre, const float* __restrict__ cw,
    const float* __restrict__ cb, unsigned short* __restrict__ xconv) {
    int idx = blockIdx.x * 256 + threadIdx.x;
    int dd = idx % 48;
    int P = idx / 48;
    int d0 = dd * 4;
    int b = P / LLEN, l = P - b * LLEN;
    int h = l / WWW, w = l - h * WWW;
    float acc0 = cb[d0], acc1 = cb[d0 + 1], acc2 = cb[d0 + 2], acc3 = cb[d0 + 3];
#pragma unroll
    for (int i = 0; i < 3; ++i) {
        int hh = h + i - 1;
        if (hh < 0 || hh >= HHH) continue;
#pragma unroll
        for (int j = 0; j < 3; ++j) {
            int ww = w + j - 1;
            if (ww < 0 || ww >= WWW) continue;
            ushort4 xv = *(const ushort4*)&xcpre[
                ((size_t)(b * LLEN + hh * WWW + ww)) * DIN + d0];
            acc0 = fmaf(bu2f(xv.x), cw[(d0 + 0) * 9 + i * 3 + j], acc0);
            acc1 = fmaf(bu2f(xv.y), cw[(d0 + 1) * 9 + i * 3 + j], acc1);
            acc2 = fmaf(bu2f(xv.z), cw[(d0 + 2) * 9 + i * 3 + j], acc2);
            acc3 = fmaf(bu2f(xv.w), cw[(d0 + 3) * 9 + i * 3 + j], acc3);
        }
    }
    acc0 = acc0 * sigm(acc0); acc1 = acc1 * sigm(acc1);
    acc2 = acc2 * sigm(acc2); acc3 = acc3 * sigm(acc3);
    ushort4 o;
    o.x = f2bu(acc0); o.y = f2bu(acc1); o.z = f2bu(acc2); o.w = f2bu(acc3);
    *(ushort4*)&xconv[(size_t)P * DIN + d0] = o;
}

// ---- K4: scan pass 1 — one segment per block, packed-fp32, fp32 h-out ------
__global__ __launch_bounds__(192) void k4_scan1(
    const bf16* __restrict__ xconv, const float* __restrict__ proj,
    const float* __restrict__ dtw, const float* __restrict__ dtb,
    const float* __restrict__ a2g, float* __restrict__ hloc,
    float* __restrict__ tsum) {
    __shared__ float pl[SEGL * PJS1];
    __shared__ int posl[SEGL];
    const int bid = blockIdx.x;              // 3584 = (b*4+k)*112 + s
    const int s = bid % SSEG;
    const int bk = bid / SSEG;
    const int k = bk & 3, b = bk >> 2;
    const int d = threadIdx.x;
    const int l0 = s * SEGL;
    for (int q = d; q < SEGL * 22; q += 192) {
        int st = q / 22, c = q - st * 22;
        int p = pos_map(k, l0 + st);
        int ofs = (c < 6) ? c : c + 2;
        pl[st * PJS1 + ofs] = proj[(size_t)(b * LLEN + p) * PJW + k * PJC + c];
    }
    if (d < SEGL) posl[d] = pos_map(k, l0 + d) * DIN;
    float w6[RDT];
#pragma unroll
    for (int r = 0; r < RDT; ++r) w6[r] = dtw[(k * DIN + d) * RDT + r];
    const float bias = dtb[k * DIN + d];
    float2 a2[8];
#pragma unroll
    for (int j = 0; j < 8; ++j)
        a2[j] = *(const float2*)&a2g[(k * DIN + d) * NST + 2 * j];
    float2 h2[8];
#pragma unroll
    for (int j = 0; j < 8; ++j) h2[j] = make_float2(0.f, 0.f);
    float T = 0.f;
    __syncthreads();
    const bf16* xg = xconv + (size_t)b * LLEN * DIN + d;
    for (int bt = 0; bt < 4; ++bt) {
        int off7[7]; float xv7[7];
#pragma unroll
        for (int i = 0; i < 7; ++i) off7[i] = posl[bt * 7 + i];
#pragma unroll
        for (int i = 0; i < 7; ++i) xv7[i] = b2f(xg[off7[i]]);
#pragma unroll
        for (int i = 0; i < 7; ++i) {
            const float* rowf = &pl[(bt * 7 + i) * PJS1];
            float4 g0 = *(const float4*)(rowf);
            float2 g1 = *(const float2*)(rowf + 4);
            float dtv = bias;
            dtv = fmaf(g0.x, w6[0], dtv); dtv = fmaf(g0.y, w6[1], dtv);
            dtv = fmaf(g0.z, w6[2], dtv); dtv = fmaf(g0.w, w6[3], dtv);
            dtv = fmaf(g1.x, w6[4], dtv); dtv = fmaf(g1.y, w6[5], dtv);
            dtv = softplusf(dtv);
            T += dtv;
            float2 dt2 = make_float2(dtv, dtv);
            float2 u2 = make_float2(dtv * xv7[i], dtv * xv7[i]);
#pragma unroll
            for (int g = 0; g < 4; ++g) {
                float4 Bv = *(const float4*)(rowf + 8 + 4 * g);
                float2 Blo = make_float2(Bv.x, Bv.y);
                float2 Bhi = make_float2(Bv.z, Bv.w);
                float2 alo = pk_mul(dt2, a2[2 * g]);
                float2 ahi = pk_mul(dt2, a2[2 * g + 1]);
                float2 elo, ehi;
                elo.x = EXP2F(alo.x); elo.y = EXP2F(alo.y);
                ehi.x = EXP2F(ahi.x); ehi.y = EXP2F(ahi.y);
                h2[2 * g]     = pk_fma(h2[2 * g],     elo, pk_mul(u2, Blo));
                h2[2 * g + 1] = pk_fma(h2[2 * g + 1], ehi, pk_mul(u2, Bhi));
            }
        }
    }
    size_t base = ((size_t)bid * DIN + d) * NST;
#pragma unroll
    for (int j = 0; j < 8; ++j) *(float2*)&hloc[base + 2 * j] = h2[j];
    tsum[bid * DIN + d] = T;
}

// ---- K5: exact segment carries (hin aliases hloc: read-before-write) -------
__global__ __launch_bounds__(256) void k5_carry(
    const float* hloc, const float* __restrict__ tsum,
    const float* __restrict__ a2g, float* hin) {
    int g = blockIdx.x * 256 + threadIdx.x;   // over B*K*D*N
    int n = g & 15;
    int dk = g >> 4;
    int d = dk % DIN;
    int bk = dk / DIN;                        // b*4 + k
    int k = bk & 3;
    float a2 = a2g[(k * DIN + d) * NST + n];
    float Hc = 0.f;
    for (int s = 0; s < SSEG; ++s) {
        int bid = bk * SSEG + s;
        size_t idx = ((size_t)bid * DIN + d) * NST + n;
        float hl = hloc[idx];
        float Tv = tsum[bid * DIN + d];
        hin[idx] = Hc;
        Hc = fmaf(EXP2F(a2 * Tv), Hc, hl);
    }
}

// ---- K6: scan pass 2 — one segment per block, packed-fp32, fp32 h-in -------
__global__ __launch_bounds__(192) void k6_scan2(
    const bf16* __restrict__ xconv, const float* __restrict__ proj,
    const float* __restrict__ dtw, const float* __restrict__ dtb,
    const float* __restrict__ a2g, const float* __restrict__ Dsp,
    const float* __restrict__ hin, bf16* __restrict__ ysm) {
    __shared__ float pl[SEGL * PJS];
    __shared__ int posl[SEGL];
    const int bid = blockIdx.x;
    const int s = bid % SSEG;
    const int bk = bid / SSEG;
    const int k = bk & 3, b = bk >> 2;
    const int d = threadIdx.x;
    const int l0 = s * SEGL;
    for (int q = d; q < SEGL * PJC; q += 192) {
        int st = q / PJC, c = q - st * PJC;
        int p = pos_map(k, l0 + st);
        int ofs = (c < 6) ? c : c + 2;
        pl[st * PJS + ofs] = proj[(size_t)(b * LLEN + p) * PJW + k * PJC + c];
    }
    if (d < SEGL) posl[d] = pos_map(k, l0 + d) * DIN;
    float w6[RDT];
#pragma unroll
    for (int r = 0; r < RDT; ++r) w6[r] = dtw[(k * DIN + d) * RDT + r];
    const float bias = dtb[k * DIN + d];
    const float dsv = Dsp[k * DIN + d];
    float2 a2[8];
#pragma unroll
    for (int j = 0; j < 8; ++j)
        a2[j] = *(const float2*)&a2g[(k * DIN + d) * NST + 2 * j];
    float2 h2[8];
    size_t hbase = ((size_t)bid * DIN + d) * NST;
#pragma unroll
    for (int j = 0; j < 8; ++j) h2[j] = *(const float2*)&hin[hbase + 2 * j];
    __syncthreads();
    const bf16* xg = xconv + (size_t)b * LLEN * DIN + d;
    bf16* ysg = ysm + ((size_t)bk * LLEN) * DIN + d;
    for (int bt = 0; bt < 4; ++bt) {
        int off7[7]; float xv7[7];
#pragma unroll
        for (int i = 0; i < 7; ++i) off7[i] = posl[bt * 7 + i];
#pragma unroll
        for (int i = 0; i < 7; ++i) xv7[i] = b2f(xg[off7[i]]);
#pragma unroll
        for (int i = 0; i < 7; ++i) {
            const float* rowf = &pl[(bt * 7 + i) * PJS];
            float4 g0 = *(const float4*)(rowf);
            float2 g1 = *(const float2*)(rowf + 4);
            float dtv = bias;
            dtv = fmaf(g0.x, w6[0], dtv); dtv = fmaf(g0.y, w6[1], dtv);
            dtv = fmaf(g0.z, w6[2], dtv); dtv = fmaf(g0.w, w6[3], dtv);
            dtv = fmaf(g1.x, w6[4], dtv); dtv = fmaf(g1.y, w6[5], dtv);
            dtv = softplusf(dtv);
            float2 dt2 = make_float2(dtv, dtv);
            float2 u2 = make_float2(dtv * xv7[i], dtv * xv7[i]);
            float2 yac0 = make_float2(0.f, 0.f), yac1 = make_float2(0.f, 0.f);
#pragma unroll
            for (int g = 0; g < 4; ++g) {
                float4 Bv = *(const float4*)(rowf + 8 + 4 * g);
                float4 Cv = *(const float4*)(rowf + 24 + 4 * g);
                float2 Blo = make_float2(Bv.x, Bv.y);
                float2 Bhi = make_float2(Bv.z, Bv.w);
                float2 Clo = make_float2(Cv.x, Cv.y);
                float2 Chi = make_float2(Cv.z, Cv.w);
                float2 alo = pk_mul(dt2, a2[2 * g]);
                float2 ahi = pk_mul(dt2, a2[2 * g + 1]);
                float2 elo, ehi;
                elo.x = EXP2F(alo.x); elo.y = EXP2F(alo.y);
                ehi.x = EXP2F(ahi.x); ehi.y = EXP2F(ahi.y);
                h2[2 * g]     = pk_fma(h2[2 * g],     elo, pk_mul(u2, Blo));
                h2[2 * g + 1] = pk_fma(h2[2 * g + 1], ehi, pk_mul(u2, Bhi));
                yac0 = pk_fma(h2[2 * g],     Clo, yac0);
                yac1 = pk_fma(h2[2 * g + 1], Chi, yac1);
            }
            float y = (yac0.x + yac0.y) + (yac1.x + yac1.y);
            ysg[off7[i]] = f2b(fmaf(dsv, xv7[i], y));
        }
    }
}

// ---- K6.5: merge 4 planes + out_norm LN + *silu(z) -------------------------
__global__ __launch_bounds__(256) void k65_merge(
    const bf16* __restrict__ ysm, const bf16* __restrict__ z,
    const float* __restrict__ onw, const float* __restrict__ onb,
    bf16* __restrict__ ymod) {
    __shared__ float rb[16 * DIN];
    __shared__ float ps[256], pq[256];
    __shared__ float mrow[16], srow[16];
    const int t = threadIdx.x;
    const int P0 = blockIdx.x * 16;
    for (int q = t; q < 16 * DIN; q += 256) {
        int pos = q / DIN, c = q - pos * DIN;
        int P = P0 + pos;
        int b = P / LLEN, l = P - b * LLEN;
        size_t base = ((size_t)(b * KDIR) * LLEN + l) * DIN + c;
        size_t pstr = (size_t)LLEN * DIN;
        float v = b2f(ysm[base]) + b2f(ysm[base + pstr]) +
                  b2f(ysm[base + 2 * pstr]) + b2f(ysm[base + 3 * pstr]);
        rb[q] = v;
    }
    __syncthreads();
    {
        int pos = t >> 4, part = t & 15;
        float s = 0.f, s2 = 0.f;
        for (int i = 0; i < 12; ++i) {
            float v = rb[pos * DIN + part * 12 + i];
            s += v; s2 += v * v;
        }
        ps[pos * 16 + part] = s; pq[pos * 16 + part] = s2;
    }
    __syncthreads();
    if (t < 16) {
        float s = 0.f, s2 = 0.f;
        for (int i = 0; i < 16; ++i) { s += ps[t * 16 + i]; s2 += pq[t * 16 + i]; }
        float m = s * (1.f / DIN);
        float v = s2 * (1.f / DIN) - m * m;
        mrow[t] = m; srow[t] = rsqrtf(v + 1e-5f);
    }
    __syncthreads();
    for (int q = t; q < 16 * DIN; q += 256) {
        int pos = q / DIN, c = q - pos * DIN;
        int P = P0 + pos;
        float v = (rb[q] - mrow[pos]) * srow[pos] * onw[c] + onb[c];
        float zv = b2f(z[(size_t)P * DIN + c]);
        v *= zv * sigm(zv);
        ymod[(size_t)P * DIN + c] = f2b(v);
    }
}

extern "C" void kernel_launch(void* const* d_in, const int* in_sizes, int n_in,
                              void* d_out, int out_size, void* d_ws, size_t ws_size,
                              hipStream_t stream) {
    const float* x      = (const float*)d_in[0];
    const float* ln1w   = (const float*)d_in[1];
    const float* ln1b   = (const float*)d_in[2];
    const float* inpW   = (const float*)d_in[3];
    const float* convW  = (const float*)d_in[4];
    const float* convB  = (const float*)d_in[5];
    const float* xprojW = (const float*)d_in[6];
    const float* dtW    = (const float*)d_in[7];
    const float* dtB    = (const float*)d_in[8];
    const float* Alog   = (const float*)d_in[9];
    const float* Dsp    = (const float*)d_in[10];
    const float* onw    = (const float*)d_in[11];
    const float* onb    = (const float*)d_in[12];
    const float* outW   = (const float*)d_in[13];
    const float* ln2w   = (const float*)d_in[14];
    const float* ln2b   = (const float*)d_in[15];
    const float* fc1W   = (const float*)d_in[16];
    const float* fc1b   = (const float*)d_in[17];
    const float* fc2W   = (const float*)d_in[18];
    const float* fc2b   = (const float*)d_in[19];
    float* out = (float*)d_out;

    char* ws = (char*)d_ws;
    // layout (byte offsets; lifetimes verified stage-by-stage):
    unsigned short* z_us    = (unsigned short*)(ws + 0);          // [G1..k65]   9,633,792
    bf16*  z_bf             = (bf16*)z_us;
    bf16*  xconv_bf         = (bf16*)(ws + 9633792);              // [k2..k6]    9,633,792
    float* proj_f           = (float*)(ws + 19267584);            // [G2..k6]   15,253,504
    bf16*  ymod_bf          = (bf16*)(ws + 19267584);             // [k65..G3]  alias proj
    unsigned short* xn_us   = (unsigned short*)(ws + 34521088);   // [LN1..G1]   4,816,896
    float* tsum_f           = (float*)(ws + 34521088);            // [k4..k5]   alias xn (2.75MB)
    unsigned short* xcpre_us= (unsigned short*)(ws + 39337984);   // [G1..k2]    9,633,792
    float* hloc_f           = (float*)(ws + 39337984);            // [k4..k6]   44,040,192 (alias dead xcpre)
    float* hin_f            = hloc_f;                             // k5 r-b-w alias
    float* y1_f             = (float*)(ws + 39337984);            // [G3..G5]   alias dead hloc
    unsigned short* y1n_us  = (unsigned short*)(ws + 48971776);   // [LN2..G4]  alias dead hloc
    bf16*  ysm_bf           = (bf16*)(ws + 83378176);             // [k6..k65]  38,535,168
    unsigned short* hmlp_us = (unsigned short*)(ws + 83378176);   // [G4..G5]   alias dead ysm
    float* a2g_f            = (float*)(ws + 121913344);           // [k0..k6]   49,152 (end 121,962,496)

    k0_pre<<<48, 256, 0, stream>>>(Alog, a2g_f);
    ln_rows<<<6272, 256, 0, stream>>>(x, ln1w, ln1b, xn_us);
    gemm_mfma<384, 96, 0><<<dim3(196, 6), 256, 0, stream>>>(
        xn_us, inpW, nullptr, nullptr, xcpre_us, z_us);
    k2_conv<<<4704, 256, 0, stream>>>(xcpre_us, convW, convB,
                                      (unsigned short*)xconv_bf);
    gemm_mfma<152, 192, 1><<<dim3(196, 3), 256, 0, stream>>>(
        (const unsigned short*)xconv_bf, xprojW, nullptr, nullptr, proj_f, nullptr);
    k4_scan1<<<3584, 192, 0, stream>>>(xconv_bf, proj_f, dtW, dtB, a2g_f,
                                       hloc_f, tsum_f);
    k5_carry<<<384, 256, 0, stream>>>(hloc_f, tsum_f, a2g_f, hin_f);
    k6_scan2<<<3584, 192, 0, stream>>>(xconv_bf, proj_f, dtW, dtB, a2g_f, Dsp,
                                       hin_f, ysm_bf);
    k65_merge<<<1568, 256, 0, stream>>>(ysm_bf, z_bf, onw, onb, ymod_bf);
    gemm_mfma<96, 192, 2><<<dim3(196, 2), 256, 0, stream>>>(
        (const unsigned short*)ymod_bf, outW, nullptr, x, y1_f, nullptr);
    ln_rows<<<6272, 256, 0, stream>>>(y1_f, ln2w, ln2b, y1n_us);
    gemm_mfma<384, 96, 3><<<dim3(196, 6), 256, 0, stream>>>(
        y1n_us, fc1W, fc1b, nullptr, hmlp_us, nullptr);
    gemm_mfma<96, 384, 4><<<dim3(196, 2), 256, 0, stream>>>(
        hmlp_us, fc2W, fc2b, y1_f, out, nullptr);
}

// Round 10
// 378.659 us; speedup vs baseline: 1.1582x; 1.0023x over previous
//
#include <hip/hip_runtime.h>
#include <hip/hip_bf16.h>

typedef __hip_bfloat16 bf16;
typedef short bf16x8 __attribute__((ext_vector_type(8)));
typedef float f32x4 __attribute__((ext_vector_type(4)));

#define BBATCH 8
#define HHH 56
#define WWW 56
#define CCH 96          // C
#define DIN 192         // D
#define NST 16          // N
#define KDIR 4          // K
#define RDT 6           // R
#define LLEN 3136       // H*W
#define BLTOT 25088     // B*L
#define SSEG 112        // segments (112 * 28 = 3136)
#define SEGL 28         // L / SSEG
#define PJC 38          // R + 2N
#define PJW 152         // K * PJC
#define PJS 40          // padded LDS row stride (16B aligned)
#define PJS1 24         // pass-1 padded row stride (r+B only)
#define MLPH 384

// native exp2/log2 (v_exp_f32 / v_log_f32) with safe fallbacks
#if defined(__has_builtin)
#if __has_builtin(__builtin_amdgcn_exp2f)
#define EXP2F(x) __builtin_amdgcn_exp2f(x)
#endif
#if __has_builtin(__builtin_amdgcn_logf)
#define LOG2F_(x) __builtin_amdgcn_logf(x)
#endif
#endif
#ifndef EXP2F
#define EXP2F(x) __expf((x) * 0.69314718056f)
#endif
#ifndef LOG2F_
#define LOG2F_(x) (__logf(x) * 1.44269504f)
#endif
#define LOG2E 1.44269504f

// packed fp32 (VOP3P, gfx90a+/gfx950)
__device__ __forceinline__ float2 pk_mul(float2 a, float2 b) {
    float2 d;
    asm("v_pk_mul_f32 %0, %1, %2" : "=v"(d) : "v"(a), "v"(b));
    return d;
}
__device__ __forceinline__ float2 pk_fma(float2 a, float2 b, float2 c) {
    float2 d;
    asm("v_pk_fma_f32 %0, %1, %2, %3" : "=v"(d) : "v"(a), "v"(b), "v"(c));
    return d;
}

__device__ __forceinline__ float b2f(bf16 v) { return __bfloat162float(v); }
__device__ __forceinline__ bf16  f2b(float v) { return __float2bfloat16(v); }
__device__ __forceinline__ unsigned short f2bu(float f) {
    union { bf16 h; unsigned short u; } c; c.h = __float2bfloat16(f); return c.u;
}
__device__ __forceinline__ float bu2f(unsigned short u) {
    union { unsigned short u; bf16 h; } c; c.u = u; return __bfloat162float(c.h);
}
__device__ __forceinline__ float sigm(float x) { return 1.f / (1.f + __expf(-x)); }
__device__ __forceinline__ float softplusf(float x) {
    float t = EXP2F(-fabsf(x) * LOG2E);
    return fmaxf(x, 0.f) + 0.69314718f * LOG2F_(1.f + t);
}
__device__ __forceinline__ float geluf(float v) {
    float u = 0.7978845608028654f * (v + 0.044715f * v * v * v);
    float ey = __expf(2.f * u);
    float th = 1.f - 2.f / (ey + 1.f);
    return 0.5f * v * (1.f + th);
}

// scan-step l -> spatial position (row-major h*56+w) for direction k
__device__ __forceinline__ int pos_map(int k, int l) {
    if (k & 2) l = LLEN - 1 - l;
    if (k & 1) { int q = l / WWW; int r = l - q * WWW; return r * WWW + q; }
    return l;
}

// ---- K0: precompute a2[k][d][n] = -exp(Alog)*log2e --------------------------
__global__ __launch_bounds__(256) void k0_pre(
    const float* __restrict__ Alog, float* __restrict__ a2g) {
    int i = blockIdx.x * 256 + threadIdx.x;   // over K*D*N = 12288
    a2g[i] = -__expf(Alog[i]) * LOG2E;
}

// ---- K0w: pre-convert the 5 GEMM weight matrices to bf16 --------------------
// layout in wbf: inpW@0(36864) xprojW@36864(29184) outW@66048(18432)
//               fc1W@84480(36864) fc2W@121344(36864)  total 158208
__global__ __launch_bounds__(256) void k0w(
    const float* __restrict__ w1, const float* __restrict__ w2,
    const float* __restrict__ w3, const float* __restrict__ w4,
    const float* __restrict__ w5, unsigned short* __restrict__ o) {
    int i = blockIdx.x * 256 + threadIdx.x;
    float v;
    if (i < 36864)       v = w1[i];
    else if (i < 66048)  v = w2[i - 36864];
    else if (i < 84480)  v = w3[i - 66048];
    else if (i < 121344) v = w4[i - 84480];
    else                 v = w5[i - 121344];
    o[i] = f2bu(v);
}

// ---- LN: one wave per row of 96, emit bf16 ---------------------------------
__global__ __launch_bounds__(256) void ln_rows(
    const float* __restrict__ xin, const float* __restrict__ w,
    const float* __restrict__ b, unsigned short* __restrict__ xn) {
    int row = blockIdx.x * 4 + (threadIdx.x >> 6);
    int lane = threadIdx.x & 63;
    const float* xr = xin + (size_t)row * 96;
    float2 v = make_float2(0.f, 0.f);
    if (lane < 48) v = *(const float2*)&xr[lane * 2];
    float s = v.x + v.y, s2 = v.x * v.x + v.y * v.y;
    for (int o = 32; o; o >>= 1) {
        s += __shfl_down(s, o);
        s2 += __shfl_down(s2, o);
    }
    s = __shfl(s, 0); s2 = __shfl(s2, 0);
    float m = s * (1.f / 96.f);
    float var = s2 * (1.f / 96.f) - m * m;
    float rs = rsqrtf(var + 1e-5f);
    if (lane < 48) {
        float o0 = (v.x - m) * rs * w[lane * 2] + b[lane * 2];
        float o1 = (v.y - m) * rs * w[lane * 2 + 1] + b[lane * 2 + 1];
        ushort2 u; u.x = f2bu(o0); u.y = f2bu(o1);
        *(ushort2*)&xn[(size_t)row * 96 + lane * 2] = u;
    }
}

// ---- Unified MFMA GEMM: C[M=25088][N] = X[M][K](bf16) . Wb[N][K]^T(bf16) ---
// block: 4 waves, each wave a 32-row M-strip, 2x4 frags -> 128M x 64N tile.
// EPI: 0=split xc/z  1=proj f32  2=+res f32  3=gelu(+bias) bf16  4=+bias+res f32
template<int N, int K, int EPI>
__global__ __launch_bounds__(256) void gemm_mfma(
    const unsigned short* __restrict__ X, const unsigned short* __restrict__ Wb,
    const float* __restrict__ bias, const float* __restrict__ res,
    void* __restrict__ out0v, void* __restrict__ out1v) {
    __shared__ unsigned short a_sh[128 * 40];
    __shared__ unsigned short b_sh[64 * 40];
    const int t = threadIdx.x;
    const int P0 = blockIdx.x * 128;
    const int N0 = blockIdx.y * 64;
    const int w = t >> 6, lane = t & 63, q = lane >> 4, nl = lane & 15;
    f32x4 acc[2][4];
#pragma unroll
    for (int i = 0; i < 2; ++i)
#pragma unroll
        for (int j = 0; j < 4; ++j)
            acc[i][j] = (f32x4){0.f, 0.f, 0.f, 0.f};
    for (int k0 = 0; k0 < K; k0 += 32) {
        __syncthreads();
        // stage A: 128 rows x 32 k (bf16 pass-through)
#pragma unroll
        for (int it = 0; it < 2; ++it) {
            int idx = t + it * 256;
            int pr = idx >> 2, kq = idx & 3;
            uint4 v = *(const uint4*)&X[(size_t)(P0 + pr) * K + k0 + kq * 8];
            *(uint4*)&a_sh[pr * 40 + kq * 8] = v;
        }
        // stage B: 64 rows x 32 k (bf16 pass-through, 1 uint4/thread)
        {
            int nr = t >> 2, kq = t & 3;
            int ng = N0 + nr; if (ng > N - 1) ng = N - 1;
            uint4 v = *(const uint4*)&Wb[(size_t)ng * K + k0 + kq * 8];
            *(uint4*)&b_sh[nr * 40 + kq * 8] = v;
        }
        __syncthreads();
        bf16x8 af[2], bfr[4];
#pragma unroll
        for (int mf = 0; mf < 2; ++mf)
            af[mf] = *(const bf16x8*)&a_sh[(w * 32 + mf * 16 + nl) * 40 + q * 8];
#pragma unroll
        for (int nf = 0; nf < 4; ++nf)
            bfr[nf] = *(const bf16x8*)&b_sh[(nf * 16 + nl) * 40 + q * 8];
#pragma unroll
        for (int mf = 0; mf < 2; ++mf)
#pragma unroll
            for (int nf = 0; nf < 4; ++nf)
                acc[mf][nf] = __builtin_amdgcn_mfma_f32_16x16x32_bf16(
                    af[mf], bfr[nf], acc[mf][nf], 0, 0, 0);
    }
#pragma unroll
    for (int mf = 0; mf < 2; ++mf) {
#pragma unroll
        for (int nf = 0; nf < 4; ++nf) {
#pragma unroll
            for (int r = 0; r < 4; ++r) {
                float v = acc[mf][nf][r];
                size_t pos = (size_t)P0 + w * 32 + mf * 16 + q * 4 + r;
                int n = N0 + nf * 16 + nl;
                if constexpr (EPI == 0) {
                    unsigned short* xc = (unsigned short*)out0v;
                    unsigned short* zz = (unsigned short*)out1v;
                    if (n < 192) xc[pos * 192 + n] = f2bu(v);
                    else         zz[pos * 192 + (n - 192)] = f2bu(v);
                } else if constexpr (EPI == 1) {
                    if (n < 152) ((float*)out0v)[pos * 152 + n] = v;
                } else if constexpr (EPI == 2) {
                    if (n < 96) ((float*)out0v)[pos * 96 + n] = res[pos * 96 + n] + v;
                } else if constexpr (EPI == 3) {
                    ((unsigned short*)out0v)[pos * 384 + n] = f2bu(geluf(v + bias[n]));
                } else {
                    if (n < 96) ((float*)out0v)[pos * 96 + n] =
                        res[pos * 96 + n] + bias[n] + v;
                }
            }
        }
    }
}

// ---- K2: depthwise 3x3 conv + bias + silu, 4 channels/thread ---------------
__global__ __launch_bounds__(256) void k2_conv(
    const unsigned short* __restrict__ xcpre, const float* __restrict__ cw,
    const float* __restrict__ cb, unsigned short* __restrict__ xconv) {
    int idx = blockIdx.x * 256 + threadIdx.x;
    int dd = idx % 48;
    int P = idx / 48;
    int d0 = dd * 4;
    int b = P / LLEN, l = P - b * LLEN;
    int h = l / WWW, w = l - h * WWW;
    float acc0 = cb[d0], acc1 = cb[d0 + 1], acc2 = cb[d0 + 2], acc3 = cb[d0 + 3];
#pragma unroll
    for (int i = 0; i < 3; ++i) {
        int hh = h + i - 1;
        if (hh < 0 || hh >= HHH) continue;
#pragma unroll
        for (int j = 0; j < 3; ++j) {
            int ww = w + j - 1;
            if (ww < 0 || ww >= WWW) continue;
            ushort4 xv = *(const ushort4*)&xcpre[
                ((size_t)(b * LLEN + hh * WWW + ww)) * DIN + d0];
            acc0 = fmaf(bu2f(xv.x), cw[(d0 + 0) * 9 + i * 3 + j], acc0);
            acc1 = fmaf(bu2f(xv.y), cw[(d0 + 1) * 9 + i * 3 + j], acc1);
            acc2 = fmaf(bu2f(xv.z), cw[(d0 + 2) * 9 + i * 3 + j], acc2);
            acc3 = fmaf(bu2f(xv.w), cw[(d0 + 3) * 9 + i * 3 + j], acc3);
        }
    }
    acc0 = acc0 * sigm(acc0); acc1 = acc1 * sigm(acc1);
    acc2 = acc2 * sigm(acc2); acc3 = acc3 * sigm(acc3);
    ushort4 o;
    o.x = f2bu(acc0); o.y = f2bu(acc1); o.z = f2bu(acc2); o.w = f2bu(acc3);
    *(ushort4*)&xconv[(size_t)P * DIN + d0] = o;
}

// ---- K4: scan pass 1 — 1-wave blocks, 64-channel chunk, packed-fp32 --------
__global__ __launch_bounds__(64) void k4_scan1(
    const bf16* __restrict__ xconv, const float* __restrict__ proj,
    const float* __restrict__ dtw, const float* __restrict__ dtb,
    const float* __restrict__ a2g, float* __restrict__ hloc,
    float* __restrict__ tsum) {
    __shared__ float pl[SEGL * PJS1];
    __shared__ int posl[SEGL];
    const int bidx = blockIdx.x;             // 10752 = 3584 segs * 3 chunks
    const int chunk = bidx % 3;
    const int seg = bidx / 3;                // (b*4+k)*112 + s
    const int s = seg % SSEG;
    const int bk = seg / SSEG;
    const int k = bk & 3, b = bk >> 2;
    const int t = threadIdx.x;
    const int d = chunk * 64 + t;
    const int l0 = s * SEGL;
    for (int q = t; q < SEGL * 22; q += 64) {
        int st = q / 22, c = q - st * 22;
        int p = pos_map(k, l0 + st);
        int ofs = (c < 6) ? c : c + 2;
        pl[st * PJS1 + ofs] = proj[(size_t)(b * LLEN + p) * PJW + k * PJC + c];
    }
    if (t < SEGL) posl[t] = pos_map(k, l0 + t) * DIN;
    float w6[RDT];
#pragma unroll
    for (int r = 0; r < RDT; ++r) w6[r] = dtw[(k * DIN + d) * RDT + r];
    const float bias = dtb[k * DIN + d];
    float2 a2[8];
#pragma unroll
    for (int j = 0; j < 8; ++j)
        a2[j] = *(const float2*)&a2g[(k * DIN + d) * NST + 2 * j];
    float2 h2[8];
#pragma unroll
    for (int j = 0; j < 8; ++j) h2[j] = make_float2(0.f, 0.f);
    float T = 0.f;
    __syncthreads();
    const bf16* xg = xconv + (size_t)b * LLEN * DIN + d;
    for (int bt = 0; bt < 4; ++bt) {
        int off7[7]; float xv7[7];
#pragma unroll
        for (int i = 0; i < 7; ++i) off7[i] = posl[bt * 7 + i];
#pragma unroll
        for (int i = 0; i < 7; ++i) xv7[i] = b2f(xg[off7[i]]);
#pragma unroll
        for (int i = 0; i < 7; ++i) {
            const float* rowf = &pl[(bt * 7 + i) * PJS1];
            float4 g0 = *(const float4*)(rowf);
            float2 g1 = *(const float2*)(rowf + 4);
            float dtv = bias;
            dtv = fmaf(g0.x, w6[0], dtv); dtv = fmaf(g0.y, w6[1], dtv);
            dtv = fmaf(g0.z, w6[2], dtv); dtv = fmaf(g0.w, w6[3], dtv);
            dtv = fmaf(g1.x, w6[4], dtv); dtv = fmaf(g1.y, w6[5], dtv);
            dtv = softplusf(dtv);
            T += dtv;
            float2 dt2 = make_float2(dtv, dtv);
            float2 u2 = make_float2(dtv * xv7[i], dtv * xv7[i]);
#pragma unroll
            for (int g = 0; g < 4; ++g) {
                float4 Bv = *(const float4*)(rowf + 8 + 4 * g);
                float2 Blo = make_float2(Bv.x, Bv.y);
                float2 Bhi = make_float2(Bv.z, Bv.w);
                float2 alo = pk_mul(dt2, a2[2 * g]);
                float2 ahi = pk_mul(dt2, a2[2 * g + 1]);
                float2 elo, ehi;
                elo.x = EXP2F(alo.x); elo.y = EXP2F(alo.y);
                ehi.x = EXP2F(ahi.x); ehi.y = EXP2F(ahi.y);
                h2[2 * g]     = pk_fma(h2[2 * g],     elo, pk_mul(u2, Blo));
                h2[2 * g + 1] = pk_fma(h2[2 * g + 1], ehi, pk_mul(u2, Bhi));
            }
        }
    }
    size_t base = ((size_t)seg * DIN + d) * NST;
#pragma unroll
    for (int j = 0; j < 8; ++j) *(float2*)&hloc[base + 2 * j] = h2[j];
    tsum[seg * DIN + d] = T;
}

// ---- K5: exact segment carries (hin aliases hloc: read-before-write) -------
__global__ __launch_bounds__(256) void k5_carry(
    const float* hloc, const float* __restrict__ tsum,
    const float* __restrict__ a2g, float* hin) {
    int g = blockIdx.x * 256 + threadIdx.x;   // over B*K*D*N
    int n = g & 15;
    int dk = g >> 4;
    int d = dk % DIN;
    int bk = dk / DIN;                        // b*4 + k
    int k = bk & 3;
    float a2 = a2g[(k * DIN + d) * NST + n];
    float Hc = 0.f;
    for (int s = 0; s < SSEG; ++s) {
        int bid = bk * SSEG + s;
        size_t idx = ((size_t)bid * DIN + d) * NST + n;
        float hl = hloc[idx];
        float Tv = tsum[bid * DIN + d];
        hin[idx] = Hc;
        Hc = fmaf(EXP2F(a2 * Tv), Hc, hl);
    }
}

// ---- K6: scan pass 2 — 1-wave blocks, 64-channel chunk, packed-fp32 --------
__global__ __launch_bounds__(64) void k6_scan2(
    const bf16* __restrict__ xconv, const float* __restrict__ proj,
    const float* __restrict__ dtw, const float* __restrict__ dtb,
    const float* __restrict__ a2g, const float* __restrict__ Dsp,
    const float* __restrict__ hin, bf16* __restrict__ ysm) {
    __shared__ float pl[SEGL * PJS];
    __shared__ int posl[SEGL];
    const int bidx = blockIdx.x;
    const int chunk = bidx % 3;
    const int seg = bidx / 3;
    const int s = seg % SSEG;
    const int bk = seg / SSEG;
    const int k = bk & 3, b = bk >> 2;
    const int t = threadIdx.x;
    const int d = chunk * 64 + t;
    const int l0 = s * SEGL;
    for (int q = t; q < SEGL * PJC; q += 64) {
        int st = q / PJC, c = q - st * PJC;
        int p = pos_map(k, l0 + st);
        int ofs = (c < 6) ? c : c + 2;
        pl[st * PJS + ofs] = proj[(size_t)(b * LLEN + p) * PJW + k * PJC + c];
    }
    if (t < SEGL) posl[t] = pos_map(k, l0 + t) * DIN;
    float w6[RDT];
#pragma unroll
    for (int r = 0; r < RDT; ++r) w6[r] = dtw[(k * DIN + d) * RDT + r];
    const float bias = dtb[k * DIN + d];
    const float dsv = Dsp[k * DIN + d];
    float2 a2[8];
#pragma unroll
    for (int j = 0; j < 8; ++j)
        a2[j] = *(const float2*)&a2g[(k * DIN + d) * NST + 2 * j];
    float2 h2[8];
    size_t hbase = ((size_t)seg * DIN + d) * NST;
#pragma unroll
    for (int j = 0; j < 8; ++j) h2[j] = *(const float2*)&hin[hbase + 2 * j];
    __syncthreads();
    const bf16* xg = xconv + (size_t)b * LLEN * DIN + d;
    bf16* ysg = ysm + ((size_t)bk * LLEN) * DIN + d;
    for (int bt = 0; bt < 4; ++bt) {
        int off7[7]; float xv7[7];
#pragma unroll
        for (int i = 0; i < 7; ++i) off7[i] = posl[bt * 7 + i];
#pragma unroll
        for (int i = 0; i < 7; ++i) xv7[i] = b2f(xg[off7[i]]);
#pragma unroll
        for (int i = 0; i < 7; ++i) {
            const float* rowf = &pl[(bt * 7 + i) * PJS];
            float4 g0 = *(const float4*)(rowf);
            float2 g1 = *(const float2*)(rowf + 4);
            float dtv = bias;
            dtv = fmaf(g0.x, w6[0], dtv); dtv = fmaf(g0.y, w6[1], dtv);
            dtv = fmaf(g0.z, w6[2], dtv); dtv = fmaf(g0.w, w6[3], dtv);
            dtv = fmaf(g1.x, w6[4], dtv); dtv = fmaf(g1.y, w6[5], dtv);
            dtv = softplusf(dtv);
            float2 dt2 = make_float2(dtv, dtv);
            float2 u2 = make_float2(dtv * xv7[i], dtv * xv7[i]);
            float2 yac0 = make_float2(0.f, 0.f), yac1 = make_float2(0.f, 0.f);
#pragma unroll
            for (int g = 0; g < 4; ++g) {
                float4 Bv = *(const float4*)(rowf + 8 + 4 * g);
                float4 Cv = *(const float4*)(rowf + 24 + 4 * g);
                float2 Blo = make_float2(Bv.x, Bv.y);
                float2 Bhi = make_float2(Bv.z, Bv.w);
                float2 Clo = make_float2(Cv.x, Cv.y);
                float2 Chi = make_float2(Cv.z, Cv.w);
                float2 alo = pk_mul(dt2, a2[2 * g]);
                float2 ahi = pk_mul(dt2, a2[2 * g + 1]);
                float2 elo, ehi;
                elo.x = EXP2F(alo.x); elo.y = EXP2F(alo.y);
                ehi.x = EXP2F(ahi.x); ehi.y = EXP2F(ahi.y);
                h2[2 * g]     = pk_fma(h2[2 * g],     elo, pk_mul(u2, Blo));
                h2[2 * g + 1] = pk_fma(h2[2 * g + 1], ehi, pk_mul(u2, Bhi));
                yac0 = pk_fma(h2[2 * g],     Clo, yac0);
                yac1 = pk_fma(h2[2 * g + 1], Chi, yac1);
            }
            float y = (yac0.x + yac0.y) + (yac1.x + yac1.y);
            ysg[off7[i]] = f2b(fmaf(dsv, xv7[i], y));
        }
    }
}

// ---- K6.5: merge 4 planes + out_norm LN + *silu(z) -------------------------
__global__ __launch_bounds__(256) void k65_merge(
    const bf16* __restrict__ ysm, const bf16* __restrict__ z,
    const float* __restrict__ onw, const float* __restrict__ onb,
    bf16* __restrict__ ymod) {
    __shared__ float rb[16 * DIN];
    __shared__ float ps[256], pq[256];
    __shared__ float mrow[16], srow[16];
    const int t = threadIdx.x;
    const int P0 = blockIdx.x * 16;
    for (int q = t; q < 16 * DIN; q += 256) {
        int pos = q / DIN, c = q - pos * DIN;
        int P = P0 + pos;
        int b = P / LLEN, l = P - b * LLEN;
        size_t base = ((size_t)(b * KDIR) * LLEN + l) * DIN + c;
        size_t pstr = (size_t)LLEN * DIN;
        float v = b2f(ysm[base]) + b2f(ysm[base + pstr]) +
                  b2f(ysm[base + 2 * pstr]) + b2f(ysm[base + 3 * pstr]);
        rb[q] = v;
    }
    __syncthreads();
    {
        int pos = t >> 4, part = t & 15;
        float s = 0.f, s2 = 0.f;
        for (int i = 0; i < 12; ++i) {
            float v = rb[pos * DIN + part * 12 + i];
            s += v; s2 += v * v;
        }
        ps[pos * 16 + part] = s; pq[pos * 16 + part] = s2;
    }
    __syncthreads();
    if (t < 16) {
        float s = 0.f, s2 = 0.f;
        for (int i = 0; i < 16; ++i) { s += ps[t * 16 + i]; s2 += pq[t * 16 + i]; }
        float m = s * (1.f / DIN);
        float v = s2 * (1.f / DIN) - m * m;
        mrow[t] = m; srow[t] = rsqrtf(v + 1e-5f);
    }
    __syncthreads();
    for (int q = t; q < 16 * DIN; q += 256) {
        int pos = q / DIN, c = q - pos * DIN;
        int P = P0 + pos;
        float v = (rb[q] - mrow[pos]) * srow[pos] * onw[c] + onb[c];
        float zv = b2f(z[(size_t)P * DIN + c]);
        v *= zv * sigm(zv);
        ymod[(size_t)P * DIN + c] = f2b(v);
    }
}

extern "C" void kernel_launch(void* const* d_in, const int* in_sizes, int n_in,
                              void* d_out, int out_size, void* d_ws, size_t ws_size,
                              hipStream_t stream) {
    const float* x      = (const float*)d_in[0];
    const float* ln1w   = (const float*)d_in[1];
    const float* ln1b   = (const float*)d_in[2];
    const float* inpW   = (const float*)d_in[3];
    const float* convW  = (const float*)d_in[4];
    const float* convB  = (const float*)d_in[5];
    const float* xprojW = (const float*)d_in[6];
    const float* dtW    = (const float*)d_in[7];
    const float* dtB    = (const float*)d_in[8];
    const float* Alog   = (const float*)d_in[9];
    const float* Dsp    = (const float*)d_in[10];
    const float* onw    = (const float*)d_in[11];
    const float* onb    = (const float*)d_in[12];
    const float* outW   = (const float*)d_in[13];
    const float* ln2w   = (const float*)d_in[14];
    const float* ln2b   = (const float*)d_in[15];
    const float* fc1W   = (const float*)d_in[16];
    const float* fc1b   = (const float*)d_in[17];
    const float* fc2W   = (const float*)d_in[18];
    const float* fc2b   = (const float*)d_in[19];
    float* out = (float*)d_out;

    char* ws = (char*)d_ws;
    // layout (byte offsets; lifetimes verified stage-by-stage):
    unsigned short* z_us    = (unsigned short*)(ws + 0);          // [G1..k65]   9,633,792
    bf16*  z_bf             = (bf16*)z_us;
    bf16*  xconv_bf         = (bf16*)(ws + 9633792);              // [k2..k6]    9,633,792
    float* proj_f           = (float*)(ws + 19267584);            // [G2..k6]   15,253,504
    bf16*  ymod_bf          = (bf16*)(ws + 19267584);             // [k65..G3]  alias proj
    unsigned short* xn_us   = (unsigned short*)(ws + 34521088);   // [LN1..G1]   4,816,896
    float* tsum_f           = (float*)(ws + 34521088);            // [k4..k5]   alias xn (2.75MB)
    unsigned short* xcpre_us= (unsigned short*)(ws + 39337984);   // [G1..k2]    9,633,792
    float* hloc_f           = (float*)(ws + 39337984);            // [k4..k6]   44,040,192 (alias dead xcpre)
    float* hin_f            = hloc_f;                             // k5 r-b-w alias
    float* y1_f             = (float*)(ws + 39337984);            // [G3..G5]   alias dead hloc
    unsigned short* y1n_us  = (unsigned short*)(ws + 48971776);   // [LN2..G4]  alias dead hloc
    bf16*  ysm_bf           = (bf16*)(ws + 83378176);             // [k6..k65]  38,535,168
    unsigned short* hmlp_us = (unsigned short*)(ws + 83378176);   // [G4..G5]   alias dead ysm
    float* a2g_f            = (float*)(ws + 121913344);           // [k0..k6]   49,152
    unsigned short* wbf_us  = (unsigned short*)(ws + 121962496);  // [k0w..G5]  316,416 (end 122,278,912)

    k0_pre<<<48, 256, 0, stream>>>(Alog, a2g_f);
    k0w<<<618, 256, 0, stream>>>(inpW, xprojW, outW, fc1W, fc2W, wbf_us);
    ln_rows<<<6272, 256, 0, stream>>>(x, ln1w, ln1b, xn_us);
    gemm_mfma<384, 96, 0><<<dim3(196, 6), 256, 0, stream>>>(
        xn_us, wbf_us + 0, nullptr, nullptr, xcpre_us, z_us);
    k2_conv<<<4704, 256, 0, stream>>>(xcpre_us, convW, convB,
                                      (unsigned short*)xconv_bf);
    gemm_mfma<152, 192, 1><<<dim3(196, 3), 256, 0, stream>>>(
        (const unsigned short*)xconv_bf, wbf_us + 36864, nullptr, nullptr,
        proj_f, nullptr);
    k4_scan1<<<10752, 64, 0, stream>>>(xconv_bf, proj_f, dtW, dtB, a2g_f,
                                       hloc_f, tsum_f);
    k5_carry<<<384, 256, 0, stream>>>(hloc_f, tsum_f, a2g_f, hin_f);
    k6_scan2<<<10752, 64, 0, stream>>>(xconv_bf, proj_f, dtW, dtB, a2g_f, Dsp,
                                       hin_f, ysm_bf);
    k65_merge<<<1568, 256, 0, stream>>>(ysm_bf, z_bf, onw, onb, ymod_bf);
    gemm_mfma<96, 192, 2><<<dim3(196, 2), 256, 0, stream>>>(
        (const unsigned short*)ymod_bf, wbf_us + 66048, nullptr, x, y1_f, nullptr);
    ln_rows<<<6272, 256, 0, stream>>>(y1_f, ln2w, ln2b, y1n_us);
    gemm_mfma<384, 96, 3><<<dim3(196, 6), 256, 0, stream>>>(
        y1n_us, wbf_us + 84480, fc1b, nullptr, hmlp_us, nullptr);
    gemm_mfma<96, 384, 4><<<dim3(196, 2), 256, 0, stream>>>(
        hmlp_us, wbf_us + 121344, fc2b, y1_f, out, nullptr);
}

// Round 11
// 370.089 us; speedup vs baseline: 1.1850x; 1.0232x over previous
//
#include <hip/hip_runtime.h>
#include <hip/hip_bf16.h>

typedef __hip_bfloat16 bf16;
typedef short bf16x8 __attribute__((ext_vector_type(8)));
typedef float f32x4 __attribute__((ext_vector_type(4)));

#define BBATCH 8
#define HHH 56
#define WWW 56
#define CCH 96          // C
#define DIN 192         // D
#define NST 16          // N
#define KDIR 4          // K
#define RDT 6           // R
#define LLEN 3136       // H*W
#define BLTOT 25088     // B*L
#define SSEG 112        // segments (112 * 28 = 3136)
#define SEGL 28         // L / SSEG
#define PJC 38          // R + 2N
#define PJW 152         // K * PJC
#define PJS 40          // padded LDS row stride (16B aligned)
#define PJS1 24         // pass-1 padded row stride (r+B only)
#define MLPH 384

// native exp2/log2 (v_exp_f32 / v_log_f32) with safe fallbacks
#if defined(__has_builtin)
#if __has_builtin(__builtin_amdgcn_exp2f)
#define EXP2F(x) __builtin_amdgcn_exp2f(x)
#endif
#if __has_builtin(__builtin_amdgcn_logf)
#define LOG2F_(x) __builtin_amdgcn_logf(x)
#endif
#endif
#ifndef EXP2F
#define EXP2F(x) __expf((x) * 0.69314718056f)
#endif
#ifndef LOG2F_
#define LOG2F_(x) (__logf(x) * 1.44269504f)
#endif
#define LOG2E 1.44269504f

// packed fp32 (VOP3P, gfx90a+/gfx950)
__device__ __forceinline__ float2 pk_mul(float2 a, float2 b) {
    float2 d;
    asm("v_pk_mul_f32 %0, %1, %2" : "=v"(d) : "v"(a), "v"(b));
    return d;
}
__device__ __forceinline__ float2 pk_fma(float2 a, float2 b, float2 c) {
    float2 d;
    asm("v_pk_fma_f32 %0, %1, %2, %3" : "=v"(d) : "v"(a), "v"(b), "v"(c));
    return d;
}

__device__ __forceinline__ float b2f(bf16 v) { return __bfloat162float(v); }
__device__ __forceinline__ bf16  f2b(float v) { return __float2bfloat16(v); }
__device__ __forceinline__ unsigned short f2bu(float f) {
    union { bf16 h; unsigned short u; } c; c.h = __float2bfloat16(f); return c.u;
}
__device__ __forceinline__ float bu2f(unsigned short u) {
    union { unsigned short u; bf16 h; } c; c.u = u; return __bfloat162float(c.h);
}
__device__ __forceinline__ float sigm(float x) { return 1.f / (1.f + __expf(-x)); }
__device__ __forceinline__ float softplusf(float x) {
    float t = EXP2F(-fabsf(x) * LOG2E);
    return fmaxf(x, 0.f) + 0.69314718f * LOG2F_(1.f + t);
}
__device__ __forceinline__ float geluf(float v) {
    float u = 0.7978845608028654f * (v + 0.044715f * v * v * v);
    float ey = __expf(2.f * u);
    float th = 1.f - 2.f / (ey + 1.f);
    return 0.5f * v * (1.f + th);
}

// scan-step l -> spatial position (row-major h*56+w) for direction k
__device__ __forceinline__ int pos_map(int k, int l) {
    if (k & 2) l = LLEN - 1 - l;
    if (k & 1) { int q = l / WWW; int r = l - q * WWW; return r * WWW + q; }
    return l;
}

// ---- K0: precompute a2[k][d][n] = -exp(Alog)*log2e --------------------------
__global__ __launch_bounds__(256) void k0_pre(
    const float* __restrict__ Alog, float* __restrict__ a2g) {
    int i = blockIdx.x * 256 + threadIdx.x;   // over K*D*N = 12288
    a2g[i] = -__expf(Alog[i]) * LOG2E;
}

// ---- K0w: pre-convert the 5 GEMM weight matrices to bf16 --------------------
// layout in wbf: inpW@0(36864) xprojW@36864(29184) outW@66048(18432)
//               fc1W@84480(36864) fc2W@121344(36864)  total 158208
__global__ __launch_bounds__(256) void k0w(
    const float* __restrict__ w1, const float* __restrict__ w2,
    const float* __restrict__ w3, const float* __restrict__ w4,
    const float* __restrict__ w5, unsigned short* __restrict__ o) {
    int i = blockIdx.x * 256 + threadIdx.x;
    float v;
    if (i < 36864)       v = w1[i];
    else if (i < 66048)  v = w2[i - 36864];
    else if (i < 84480)  v = w3[i - 66048];
    else if (i < 121344) v = w4[i - 84480];
    else                 v = w5[i - 121344];
    o[i] = f2bu(v);
}

// ---- Unified MFMA GEMM: C[M=25088][N] = A[M][K] . Wb[N][K]^T(bf16) ---------
// block: 4 waves, each wave a 32-row M-strip, 2x4 frags -> 128M x 64N tile.
// LNIN: A is f32 (K=96) with LayerNorm fused during staging.
// EPI: 0=split xc/z  1=proj f32  2=+res f32  3=gelu(+bias) bf16  4=+bias+res f32
template<int N, int K, int EPI, bool LNIN>
__global__ __launch_bounds__(256) void gemm_mfma(
    const void* __restrict__ Xv, const unsigned short* __restrict__ Wb,
    const float* __restrict__ bias, const float* __restrict__ res,
    const float* __restrict__ lnw, const float* __restrict__ lnb,
    void* __restrict__ out0v, void* __restrict__ out1v) {
    __shared__ unsigned short a_sh[128 * 40];
    __shared__ unsigned short b_sh[64 * 40];
    __shared__ float mrow[128], rrow[128];
    __shared__ float lnw_sh[96], lnb_sh[96];
    const int t = threadIdx.x;
    const int P0 = blockIdx.x * 128;
    const int N0 = blockIdx.y * 64;
    const int w = t >> 6, lane = t & 63, q = lane >> 4, nl = lane & 15;
    if constexpr (LNIN) {
        // row stats: 2 threads per row, 48 elems each
        const float* Xf = (const float*)Xv;
        const float* xr = Xf + (size_t)(P0 + (t >> 1)) * 96 + (t & 1) * 48;
        float s = 0.f, s2 = 0.f;
#pragma unroll
        for (int i = 0; i < 12; ++i) {
            float4 v = *(const float4*)&xr[i * 4];
            s += v.x + v.y + v.z + v.w;
            s2 += v.x * v.x + v.y * v.y + v.z * v.z + v.w * v.w;
        }
        s += __shfl_xor(s, 1); s2 += __shfl_xor(s2, 1);
        if ((t & 1) == 0) {
            float m = s * (1.f / 96.f);
            float var = s2 * (1.f / 96.f) - m * m;
            mrow[t >> 1] = m; rrow[t >> 1] = rsqrtf(var + 1e-5f);
        }
        if (t < 96) { lnw_sh[t] = lnw[t]; lnb_sh[t] = lnb[t]; }
    }
    f32x4 acc[2][4];
#pragma unroll
    for (int i = 0; i < 2; ++i)
#pragma unroll
        for (int j = 0; j < 4; ++j)
            acc[i][j] = (f32x4){0.f, 0.f, 0.f, 0.f};
    for (int k0 = 0; k0 < K; k0 += 32) {
        __syncthreads();
        // stage A: 128 rows x 32 k
#pragma unroll
        for (int it = 0; it < 2; ++it) {
            int idx = t + it * 256;
            int pr = idx >> 2, kq = idx & 3;
            if constexpr (LNIN) {
                const float* Xf = (const float*)Xv;
                const float* src = &Xf[(size_t)(P0 + pr) * K + k0 + kq * 8];
                float m = mrow[pr], r = rrow[pr];
                float4 v0 = *(const float4*)src;
                float4 v1 = *(const float4*)(src + 4);
                int c0 = k0 + kq * 8;
                ushort4 u0, u1;
                u0.x = f2bu((v0.x - m) * r * lnw_sh[c0+0] + lnb_sh[c0+0]);
                u0.y = f2bu((v0.y - m) * r * lnw_sh[c0+1] + lnb_sh[c0+1]);
                u0.z = f2bu((v0.z - m) * r * lnw_sh[c0+2] + lnb_sh[c0+2]);
                u0.w = f2bu((v0.w - m) * r * lnw_sh[c0+3] + lnb_sh[c0+3]);
                u1.x = f2bu((v1.x - m) * r * lnw_sh[c0+4] + lnb_sh[c0+4]);
                u1.y = f2bu((v1.y - m) * r * lnw_sh[c0+5] + lnb_sh[c0+5]);
                u1.z = f2bu((v1.z - m) * r * lnw_sh[c0+6] + lnb_sh[c0+6]);
                u1.w = f2bu((v1.w - m) * r * lnw_sh[c0+7] + lnb_sh[c0+7]);
                *(ushort4*)&a_sh[pr * 40 + kq * 8] = u0;
                *(ushort4*)&a_sh[pr * 40 + kq * 8 + 4] = u1;
            } else {
                const unsigned short* X = (const unsigned short*)Xv;
                uint4 v = *(const uint4*)&X[(size_t)(P0 + pr) * K + k0 + kq * 8];
                *(uint4*)&a_sh[pr * 40 + kq * 8] = v;
            }
        }
        // stage B: 64 rows x 32 k (bf16 pass-through, 1 uint4/thread)
        {
            int nr = t >> 2, kq = t & 3;
            int ng = N0 + nr; if (ng > N - 1) ng = N - 1;
            uint4 v = *(const uint4*)&Wb[(size_t)ng * K + k0 + kq * 8];
            *(uint4*)&b_sh[nr * 40 + kq * 8] = v;
        }
        __syncthreads();
        bf16x8 af[2], bfr[4];
#pragma unroll
        for (int mf = 0; mf < 2; ++mf)
            af[mf] = *(const bf16x8*)&a_sh[(w * 32 + mf * 16 + nl) * 40 + q * 8];
#pragma unroll
        for (int nf = 0; nf < 4; ++nf)
            bfr[nf] = *(const bf16x8*)&b_sh[(nf * 16 + nl) * 40 + q * 8];
#pragma unroll
        for (int mf = 0; mf < 2; ++mf)
#pragma unroll
            for (int nf = 0; nf < 4; ++nf)
                acc[mf][nf] = __builtin_amdgcn_mfma_f32_16x16x32_bf16(
                    af[mf], bfr[nf], acc[mf][nf], 0, 0, 0);
    }
#pragma unroll
    for (int mf = 0; mf < 2; ++mf) {
#pragma unroll
        for (int nf = 0; nf < 4; ++nf) {
#pragma unroll
            for (int r = 0; r < 4; ++r) {
                float v = acc[mf][nf][r];
                size_t pos = (size_t)P0 + w * 32 + mf * 16 + q * 4 + r;
                int n = N0 + nf * 16 + nl;
                if constexpr (EPI == 0) {
                    unsigned short* xc = (unsigned short*)out0v;
                    unsigned short* zz = (unsigned short*)out1v;
                    if (n < 192) xc[pos * 192 + n] = f2bu(v);
                    else         zz[pos * 192 + (n - 192)] = f2bu(v);
                } else if constexpr (EPI == 1) {
                    if (n < 152) ((float*)out0v)[pos * 152 + n] = v;
                } else if constexpr (EPI == 2) {
                    if (n < 96) ((float*)out0v)[pos * 96 + n] = res[pos * 96 + n] + v;
                } else if constexpr (EPI == 3) {
                    ((unsigned short*)out0v)[pos * 384 + n] = f2bu(geluf(v + bias[n]));
                } else {
                    if (n < 96) ((float*)out0v)[pos * 96 + n] =
                        res[pos * 96 + n] + bias[n] + v;
                }
            }
        }
    }
}

// ---- K2: depthwise 3x3 conv + bias + silu, 4 channels/thread ---------------
__global__ __launch_bounds__(256) void k2_conv(
    const unsigned short* __restrict__ xcpre, const float* __restrict__ cw,
    const float* __restrict__ cb, unsigned short* __restrict__ xconv) {
    int idx = blockIdx.x * 256 + threadIdx.x;
    int dd = idx % 48;
    int P = idx / 48;
    int d0 = dd * 4;
    int b = P / LLEN, l = P - b * LLEN;
    int h = l / WWW, w = l - h * WWW;
    float acc0 = cb[d0], acc1 = cb[d0 + 1], acc2 = cb[d0 + 2], acc3 = cb[d0 + 3];
#pragma unroll
    for (int i = 0; i < 3; ++i) {
        int hh = h + i - 1;
        if (hh < 0 || hh >= HHH) continue;
#pragma unroll
        for (int j = 0; j < 3; ++j) {
            int ww = w + j - 1;
            if (ww < 0 || ww >= WWW) continue;
            ushort4 xv = *(const ushort4*)&xcpre[
                ((size_t)(b * LLEN + hh * WWW + ww)) * DIN + d0];
            acc0 = fmaf(bu2f(xv.x), cw[(d0 + 0) * 9 + i * 3 + j], acc0);
            acc1 = fmaf(bu2f(xv.y), cw[(d0 + 1) * 9 + i * 3 + j], acc1);
            acc2 = fmaf(bu2f(xv.z), cw[(d0 + 2) * 9 + i * 3 + j], acc2);
            acc3 = fmaf(bu2f(xv.w), cw[(d0 + 3) * 9 + i * 3 + j], acc3);
        }
    }
    acc0 = acc0 * sigm(acc0); acc1 = acc1 * sigm(acc1);
    acc2 = acc2 * sigm(acc2); acc3 = acc3 * sigm(acc3);
    ushort4 o;
    o.x = f2bu(acc0); o.y = f2bu(acc1); o.z = f2bu(acc2); o.w = f2bu(acc3);
    *(ushort4*)&xconv[(size_t)P * DIN + d0] = o;
}

// ---- K4: scan pass 1 — one segment per block, packed-fp32, fp32 h-out ------
__global__ __launch_bounds__(192) void k4_scan1(
    const bf16* __restrict__ xconv, const float* __restrict__ proj,
    const float* __restrict__ dtw, const float* __restrict__ dtb,
    const float* __restrict__ a2g, float* __restrict__ hloc,
    float* __restrict__ tsum) {
    __shared__ float pl[SEGL * PJS1];
    __shared__ int posl[SEGL];
    const int bid = blockIdx.x;              // 3584 = (b*4+k)*112 + s
    const int s = bid % SSEG;
    const int bk = bid / SSEG;
    const int k = bk & 3, b = bk >> 2;
    const int d = threadIdx.x;
    const int l0 = s * SEGL;
    for (int q = d; q < SEGL * 22; q += 192) {
        int st = q / 22, c = q - st * 22;
        int p = pos_map(k, l0 + st);
        int ofs = (c < 6) ? c : c + 2;
        pl[st * PJS1 + ofs] = proj[(size_t)(b * LLEN + p) * PJW + k * PJC + c];
    }
    if (d < SEGL) posl[d] = pos_map(k, l0 + d) * DIN;
    float w6[RDT];
#pragma unroll
    for (int r = 0; r < RDT; ++r) w6[r] = dtw[(k * DIN + d) * RDT + r];
    const float bias = dtb[k * DIN + d];
    float2 a2[8];
#pragma unroll
    for (int j = 0; j < 8; ++j)
        a2[j] = *(const float2*)&a2g[(k * DIN + d) * NST + 2 * j];
    float2 h2[8];
#pragma unroll
    for (int j = 0; j < 8; ++j) h2[j] = make_float2(0.f, 0.f);
    float T = 0.f;
    __syncthreads();
    const bf16* xg = xconv + (size_t)b * LLEN * DIN + d;
    for (int bt = 0; bt < 4; ++bt) {
        int off7[7]; float xv7[7];
#pragma unroll
        for (int i = 0; i < 7; ++i) off7[i] = posl[bt * 7 + i];
#pragma unroll
        for (int i = 0; i < 7; ++i) xv7[i] = b2f(xg[off7[i]]);
#pragma unroll
        for (int i = 0; i < 7; ++i) {
            const float* rowf = &pl[(bt * 7 + i) * PJS1];
            float4 g0 = *(const float4*)(rowf);
            float2 g1 = *(const float2*)(rowf + 4);
            float dtv = bias;
            dtv = fmaf(g0.x, w6[0], dtv); dtv = fmaf(g0.y, w6[1], dtv);
            dtv = fmaf(g0.z, w6[2], dtv); dtv = fmaf(g0.w, w6[3], dtv);
            dtv = fmaf(g1.x, w6[4], dtv); dtv = fmaf(g1.y, w6[5], dtv);
            dtv = softplusf(dtv);
            T += dtv;
            float2 dt2 = make_float2(dtv, dtv);
            float2 u2 = make_float2(dtv * xv7[i], dtv * xv7[i]);
#pragma unroll
            for (int g = 0; g < 4; ++g) {
                float4 Bv = *(const float4*)(rowf + 8 + 4 * g);
                float2 Blo = make_float2(Bv.x, Bv.y);
                float2 Bhi = make_float2(Bv.z, Bv.w);
                float2 alo = pk_mul(dt2, a2[2 * g]);
                float2 ahi = pk_mul(dt2, a2[2 * g + 1]);
                float2 elo, ehi;
                elo.x = EXP2F(alo.x); elo.y = EXP2F(alo.y);
                ehi.x = EXP2F(ahi.x); ehi.y = EXP2F(ahi.y);
                h2[2 * g]     = pk_fma(h2[2 * g],     elo, pk_mul(u2, Blo));
                h2[2 * g + 1] = pk_fma(h2[2 * g + 1], ehi, pk_mul(u2, Bhi));
            }
        }
    }
    size_t base = ((size_t)bid * DIN + d) * NST;
#pragma unroll
    for (int j = 0; j < 8; ++j) *(float2*)&hloc[base + 2 * j] = h2[j];
    tsum[bid * DIN + d] = T;
}

// ---- K5: exact segment carries (hin aliases hloc: read-before-write) -------
__global__ __launch_bounds__(256) void k5_carry(
    const float* hloc, const float* __restrict__ tsum,
    const float* __restrict__ a2g, float* hin) {
    int g = blockIdx.x * 256 + threadIdx.x;   // over B*K*D*N
    int n = g & 15;
    int dk = g >> 4;
    int d = dk % DIN;
    int bk = dk / DIN;                        // b*4 + k
    int k = bk & 3;
    float a2 = a2g[(k * DIN + d) * NST + n];
    float Hc = 0.f;
    for (int s = 0; s < SSEG; ++s) {
        int bid = bk * SSEG + s;
        size_t idx = ((size_t)bid * DIN + d) * NST + n;
        float hl = hloc[idx];
        float Tv = tsum[bid * DIN + d];
        hin[idx] = Hc;
        Hc = fmaf(EXP2F(a2 * Tv), Hc, hl);
    }
}

// ---- K6: scan pass 2 — one segment per block, packed-fp32, fp32 h-in -------
__global__ __launch_bounds__(192) void k6_scan2(
    const bf16* __restrict__ xconv, const float* __restrict__ proj,
    const float* __restrict__ dtw, const float* __restrict__ dtb,
    const float* __restrict__ a2g, const float* __restrict__ Dsp,
    const float* __restrict__ hin, bf16* __restrict__ ysm) {
    __shared__ float pl[SEGL * PJS];
    __shared__ int posl[SEGL];
    const int bid = blockIdx.x;
    const int s = bid % SSEG;
    const int bk = bid / SSEG;
    const int k = bk & 3, b = bk >> 2;
    const int d = threadIdx.x;
    const int l0 = s * SEGL;
    for (int q = d; q < SEGL * PJC; q += 192) {
        int st = q / PJC, c = q - st * PJC;
        int p = pos_map(k, l0 + st);
        int ofs = (c < 6) ? c : c + 2;
        pl[st * PJS + ofs] = proj[(size_t)(b * LLEN + p) * PJW + k * PJC + c];
    }
    if (d < SEGL) posl[d] = pos_map(k, l0 + d) * DIN;
    float w6[RDT];
#pragma unroll
    for (int r = 0; r < RDT; ++r) w6[r] = dtw[(k * DIN + d) * RDT + r];
    const float bias = dtb[k * DIN + d];
    const float dsv = Dsp[k * DIN + d];
    float2 a2[8];
#pragma unroll
    for (int j = 0; j < 8; ++j)
        a2[j] = *(const float2*)&a2g[(k * DIN + d) * NST + 2 * j];
    float2 h2[8];
    size_t hbase = ((size_t)bid * DIN + d) * NST;
#pragma unroll
    for (int j = 0; j < 8; ++j) h2[j] = *(const float2*)&hin[hbase + 2 * j];
    __syncthreads();
    const bf16* xg = xconv + (size_t)b * LLEN * DIN + d;
    bf16* ysg = ysm + ((size_t)bk * LLEN) * DIN + d;
    for (int bt = 0; bt < 4; ++bt) {
        int off7[7]; float xv7[7];
#pragma unroll
        for (int i = 0; i < 7; ++i) off7[i] = posl[bt * 7 + i];
#pragma unroll
        for (int i = 0; i < 7; ++i) xv7[i] = b2f(xg[off7[i]]);
#pragma unroll
        for (int i = 0; i < 7; ++i) {
            const float* rowf = &pl[(bt * 7 + i) * PJS];
            float4 g0 = *(const float4*)(rowf);
            float2 g1 = *(const float2*)(rowf + 4);
            float dtv = bias;
            dtv = fmaf(g0.x, w6[0], dtv); dtv = fmaf(g0.y, w6[1], dtv);
            dtv = fmaf(g0.z, w6[2], dtv); dtv = fmaf(g0.w, w6[3], dtv);
            dtv = fmaf(g1.x, w6[4], dtv); dtv = fmaf(g1.y, w6[5], dtv);
            dtv = softplusf(dtv);
            float2 dt2 = make_float2(dtv, dtv);
            float2 u2 = make_float2(dtv * xv7[i], dtv * xv7[i]);
            float2 yac0 = make_float2(0.f, 0.f), yac1 = make_float2(0.f, 0.f);
#pragma unroll
            for (int g = 0; g < 4; ++g) {
                float4 Bv = *(const float4*)(rowf + 8 + 4 * g);
                float4 Cv = *(const float4*)(rowf + 24 + 4 * g);
                float2 Blo = make_float2(Bv.x, Bv.y);
                float2 Bhi = make_float2(Bv.z, Bv.w);
                float2 Clo = make_float2(Cv.x, Cv.y);
                float2 Chi = make_float2(Cv.z, Cv.w);
                float2 alo = pk_mul(dt2, a2[2 * g]);
                float2 ahi = pk_mul(dt2, a2[2 * g + 1]);
                float2 elo, ehi;
                elo.x = EXP2F(alo.x); elo.y = EXP2F(alo.y);
                ehi.x = EXP2F(ahi.x); ehi.y = EXP2F(ahi.y);
                h2[2 * g]     = pk_fma(h2[2 * g],     elo, pk_mul(u2, Blo));
                h2[2 * g + 1] = pk_fma(h2[2 * g + 1], ehi, pk_mul(u2, Bhi));
                yac0 = pk_fma(h2[2 * g],     Clo, yac0);
                yac1 = pk_fma(h2[2 * g + 1], Chi, yac1);
            }
            float y = (yac0.x + yac0.y) + (yac1.x + yac1.y);
            ysg[off7[i]] = f2b(fmaf(dsv, xv7[i], y));
        }
    }
}

// ---- K6.5: merge 4 planes + out_norm LN + *silu(z) -------------------------
__global__ __launch_bounds__(256) void k65_merge(
    const bf16* __restrict__ ysm, const bf16* __restrict__ z,
    const float* __restrict__ onw, const float* __restrict__ onb,
    bf16* __restrict__ ymod) {
    __shared__ float rb[16 * DIN];
    __shared__ float ps[256], pq[256];
    __shared__ float mrow[16], srow[16];
    const int t = threadIdx.x;
    const int P0 = blockIdx.x * 16;
    for (int q = t; q < 16 * DIN; q += 256) {
        int pos = q / DIN, c = q - pos * DIN;
        int P = P0 + pos;
        int b = P / LLEN, l = P - b * LLEN;
        size_t base = ((size_t)(b * KDIR) * LLEN + l) * DIN + c;
        size_t pstr = (size_t)LLEN * DIN;
        float v = b2f(ysm[base]) + b2f(ysm[base + pstr]) +
                  b2f(ysm[base + 2 * pstr]) + b2f(ysm[base + 3 * pstr]);
        rb[q] = v;
    }
    __syncthreads();
    {
        int pos = t >> 4, part = t & 15;
        float s = 0.f, s2 = 0.f;
        for (int i = 0; i < 12; ++i) {
            float v = rb[pos * DIN + part * 12 + i];
            s += v; s2 += v * v;
        }
        ps[pos * 16 + part] = s; pq[pos * 16 + part] = s2;
    }
    __syncthreads();
    if (t < 16) {
        float s = 0.f, s2 = 0.f;
        for (int i = 0; i < 16; ++i) { s += ps[t * 16 + i]; s2 += pq[t * 16 + i]; }
        float m = s * (1.f / DIN);
        float v = s2 * (1.f / DIN) - m * m;
        mrow[t] = m; srow[t] = rsqrtf(v + 1e-5f);
    }
    __syncthreads();
    for (int q = t; q < 16 * DIN; q += 256) {
        int pos = q / DIN, c = q - pos * DIN;
        int P = P0 + pos;
        float v = (rb[q] - mrow[pos]) * srow[pos] * onw[c] + onb[c];
        float zv = b2f(z[(size_t)P * DIN + c]);
        v *= zv * sigm(zv);
        ymod[(size_t)P * DIN + c] = f2b(v);
    }
}

extern "C" void kernel_launch(void* const* d_in, const int* in_sizes, int n_in,
                              void* d_out, int out_size, void* d_ws, size_t ws_size,
                              hipStream_t stream) {
    const float* x      = (const float*)d_in[0];
    const float* ln1w   = (const float*)d_in[1];
    const float* ln1b   = (const float*)d_in[2];
    const float* inpW   = (const float*)d_in[3];
    const float* convW  = (const float*)d_in[4];
    const float* convB  = (const float*)d_in[5];
    const float* xprojW = (const float*)d_in[6];
    const float* dtW    = (const float*)d_in[7];
    const float* dtB    = (const float*)d_in[8];
    const float* Alog   = (const float*)d_in[9];
    const float* Dsp    = (const float*)d_in[10];
    const float* onw    = (const float*)d_in[11];
    const float* onb    = (const float*)d_in[12];
    const float* outW   = (const float*)d_in[13];
    const float* ln2w   = (const float*)d_in[14];
    const float* ln2b   = (const float*)d_in[15];
    const float* fc1W   = (const float*)d_in[16];
    const float* fc1b   = (const float*)d_in[17];
    const float* fc2W   = (const float*)d_in[18];
    const float* fc2b   = (const float*)d_in[19];
    float* out = (float*)d_out;

    char* ws = (char*)d_ws;
    // layout (byte offsets; lifetimes verified stage-by-stage):
    unsigned short* z_us    = (unsigned short*)(ws + 0);          // [G1..k65]   9,633,792
    bf16*  z_bf             = (bf16*)z_us;
    bf16*  xconv_bf         = (bf16*)(ws + 9633792);              // [k2..k6]    9,633,792
    float* proj_f           = (float*)(ws + 19267584);            // [G2..k6]   15,253,504
    bf16*  ymod_bf          = (bf16*)(ws + 19267584);             // [k65..G3]  alias proj
    float* tsum_f           = (float*)(ws + 34521088);            // [k4..k5]    2,752,512
    unsigned short* xcpre_us= (unsigned short*)(ws + 39337984);   // [G1..k2]    9,633,792
    float* hloc_f           = (float*)(ws + 39337984);            // [k4..k6]   44,040,192 (alias dead xcpre)
    float* hin_f            = hloc_f;                             // k5 r-b-w alias
    float* y1_f             = (float*)(ws + 39337984);            // [G3..G5]   alias dead hloc
    bf16*  ysm_bf           = (bf16*)(ws + 83378176);             // [k6..k65]  38,535,168
    unsigned short* hmlp_us = (unsigned short*)(ws + 83378176);   // [G4..G5]   alias dead ysm
    float* a2g_f            = (float*)(ws + 121913344);           // [k0..k6]   49,152
    unsigned short* wbf_us  = (unsigned short*)(ws + 121962496);  // [k0w..G5]  316,416 (end 122,278,912)

    k0_pre<<<48, 256, 0, stream>>>(Alog, a2g_f);
    k0w<<<618, 256, 0, stream>>>(inpW, xprojW, outW, fc1W, fc2W, wbf_us);
    gemm_mfma<384, 96, 0, true><<<dim3(196, 6), 256, 0, stream>>>(
        x, wbf_us + 0, nullptr, nullptr, ln1w, ln1b, xcpre_us, z_us);
    k2_conv<<<4704, 256, 0, stream>>>(xcpre_us, convW, convB,
                                      (unsigned short*)xconv_bf);
    gemm_mfma<152, 192, 1, false><<<dim3(196, 3), 256, 0, stream>>>(
        xconv_bf, wbf_us + 36864, nullptr, nullptr, nullptr, nullptr,
        proj_f, nullptr);
    k4_scan1<<<3584, 192, 0, stream>>>(xconv_bf, proj_f, dtW, dtB, a2g_f,
                                       hloc_f, tsum_f);
    k5_carry<<<384, 256, 0, stream>>>(hloc_f, tsum_f, a2g_f, hin_f);
    k6_scan2<<<3584, 192, 0, stream>>>(xconv_bf, proj_f, dtW, dtB, a2g_f, Dsp,
                                       hin_f, ysm_bf);
    k65_merge<<<1568, 256, 0, stream>>>(ysm_bf, z_bf, onw, onb, ymod_bf);
    gemm_mfma<96, 192, 2, false><<<dim3(196, 2), 256, 0, stream>>>(
        ymod_bf, wbf_us + 66048, nullptr, x, nullptr, nullptr, y1_f, nullptr);
    gemm_mfma<384, 96, 3, true><<<dim3(196, 6), 256, 0, stream>>>(
        y1_f, wbf_us + 84480, fc1b, nullptr, ln2w, ln2b, hmlp_us, nullptr);
    gemm_mfma<96, 384, 4, false><<<dim3(196, 2), 256, 0, stream>>>(
        hmlp_us, wbf_us + 121344, fc2b, y1_f, nullptr, nullptr, out, nullptr);
}